// Round 18
// baseline (334.101 us; speedup 1.0000x reference)
//
#include <hip/hip_runtime.h>
#include <hip/hip_bf16.h>
#include <stdint.h>

typedef unsigned int uint32;
typedef unsigned short u16;
typedef __attribute__((ext_vector_type(8))) short bf16x8;
typedef __attribute__((ext_vector_type(4))) float f32x4;
typedef __attribute__((ext_vector_type(2))) float f32x2;
typedef uint32 u32x4 __attribute__((ext_vector_type(4)));

#define N_NODES 50000
#define NP      50048                 // padded row count (391*128)
#define N_EDGES 800000
#define ETOT    (N_EDGES + N_NODES)
#define F_INN   78
#define H1      10
#define D1      780
#define OUT2    128
#define NGRAPH  512
#define NEG_SLOPE 0.2f
#define PL40    ((size_t)NP * 40)     // uints per padded head-plane

__device__ __forceinline__ float lrelu(float v) { return v > 0.f ? v : NEG_SLOPE * v; }
__device__ __forceinline__ u16 f2bfbits(float f) {
    return __bfloat16_as_ushort(__float2bfloat16(f));
}
__device__ __forceinline__ uint32 packbf(float lo, float hi) {
    return (uint32)f2bfbits(lo) | ((uint32)f2bfbits(hi) << 16);
}
__device__ __forceinline__ f32x2 bf2(uint32 u) {
    __hip_bfloat162 b = *reinterpret_cast<__hip_bfloat162*>(&u);
    float2 t = __bfloat1622float2(b);
    return (f32x2){t.x, t.y};
}
__device__ __forceinline__ int esrc(const int* ei, int e) { return e < N_EDGES ? ei[e] : e - N_EDGES; }
__device__ __forceinline__ int edst(const int* ei, int e) { return e < N_EDGES ? ei[N_EDGES + e] : e - N_EDGES; }

// async global->LDS 16B per lane: lane i moves g[lane*16B] -> lds_base + lane*16B
typedef __attribute__((address_space(1))) const uint32 guint;
typedef __attribute__((address_space(3))) uint32 luint;
__device__ __forceinline__ void cp16(uint32* lds, const uint32* g, int lane) {
    __builtin_amdgcn_global_load_lds((guint*)(g + lane * 4), (luint*)lds, 16, 0, 0);
}

// ---------------- prep: xbp [NP][80 u16], w1p [10][80][80 u16], w2p [10][128][80 u16] ----------------
// NOTE: xbp feat 78 is set to bf16(1.0): agg1m uses that column to get the softmax
// denominator for free (C[h][78] = sum of weights). alphas1x is unaffected (VAT col 78 = 0),
// gemmf is unaffected (w1p rows 78/79 = 0).
#define NXP (N_NODES * 80)
__global__ __launch_bounds__(256) void prep_kernel(const float* __restrict__ x,
                                                   const float* __restrict__ W1,
                                                   const float* __restrict__ W2,
                                                   u16* __restrict__ xbp,
                                                   u16* __restrict__ w1p,
                                                   u16* __restrict__ w2p) {
    const int total = NXP + 10 * 80 * 80 + 10 * 128 * 80;
    for (int id = blockIdx.x * 256 + threadIdx.x; id < total; id += gridDim.x * 256) {
        if (id < NXP) {
            int n = id / 80, k = id - n * 80;
            xbp[id] = (k < 78) ? f2bfbits(x[n * 78 + k]) : ((k == 78) ? (u16)0x3F80 : (u16)0);
        } else if (id < NXP + 64000) {
            int t = id - NXP;
            int h = t / 6400, r = t - h * 6400;
            int n = r / 80, k = r - n * 80;
            w1p[t] = (n < 78 && k < 78) ? f2bfbits(W1[k * D1 + h * 78 + n]) : (u16)0;
        } else {
            int t = id - NXP - 64000;
            int h = t / 10240, r = t - h * 10240;
            int n = r / 80, k = r - n * 80;
            w2p[t] = (k < 78) ? f2bfbits(W2[(h * 78 + k) * OUT2 + n]) : (u16)0;
        }
    }
}

// ---------------- prep2: VAT [32][80 u16] padded + w2as/w2ad ----------------
__global__ __launch_bounds__(256) void prep2_kernel(const float* __restrict__ W1,
                                                    const float* __restrict__ a_src1,
                                                    const float* __restrict__ a_dst1,
                                                    const float* __restrict__ W2,
                                                    const float* __restrict__ a_src2,
                                                    const float* __restrict__ a_dst2,
                                                    u16* __restrict__ VAT,
                                                    float* __restrict__ w2as,
                                                    float* __restrict__ w2ad) {
    int gid = blockIdx.x * 256 + threadIdx.x;
    int gs = gridDim.x * 256;
    for (int idx = gid; idx < 32 * 80; idx += gs) {
        int j = idx / 80, k = idx - j * 80;
        float s = 0.f;
        if (j < 20 && k < 78) {
            int h = (j < 10) ? j : j - 10;
            const float* vec = ((j < 10) ? a_src1 : a_dst1) + h * F_INN;
            const float* wrow = W1 + k * D1 + h * F_INN;
            for (int f = 0; f < F_INN; ++f) s = fmaf(wrow[f], vec[f], s);
            VAT[idx] = f2bfbits(s);
        } else {
            VAT[idx] = 0;
        }
    }
    for (int c = gid; c < D1; c += gs) {
        const float* r0 = W2 + (size_t)c * OUT2;
        float s = 0.f, d = 0.f;
        for (int j = 0; j < OUT2; ++j) {
            s = fmaf(r0[j], a_src2[j], s);
            d = fmaf(r0[j], a_dst2[j], d);
        }
        w2as[c] = s;
        w2ad[c] = d;
    }
}

// ---------------- alphas1x: xbp[128 rows] @ VAT^T -> asd1[N][20] + compact asrc[N][12] ----------------
__global__ __launch_bounds__(256) void alphas1x_kernel(const uint32* __restrict__ xbu,
                                                       const uint32* __restrict__ vatu,
                                                       float* __restrict__ asd1,
                                                       float* __restrict__ asrc) {
    __shared__ uint32 As[5136];
    __shared__ uint32 Bs[1296];
    int tid = threadIdx.x, lane = tid & 63, wv = tid >> 6;
    int row0 = blockIdx.x * 128;
    const uint32* aplane = xbu + (size_t)row0 * 40;

#pragma unroll
    for (int t = 0; t < 5; ++t)
        cp16(As + wv * 1280 + t * 256, aplane + wv * 1280 + t * 256, lane);
    if (wv == 0) {
#pragma unroll
        for (int t = 0; t < 5; ++t)
            cp16(Bs + t * 256, vatu + t * 256, lane);
    }
    __syncthreads();

    int l15 = lane & 15, quad = lane >> 4;
    const u16* Asu = (const u16*)As;
    const u16* Bsu = (const u16*)Bs;
    f32x4 acc[2][2];
#pragma unroll
    for (int mi = 0; mi < 2; ++mi)
#pragma unroll
        for (int nj = 0; nj < 2; ++nj) acc[mi][nj] = (f32x4){0.f, 0.f, 0.f, 0.f};

    int abase[2], bbase[2];
#pragma unroll
    for (int mi = 0; mi < 2; ++mi) abase[mi] = (wv * 32 + mi * 16 + l15) * 80 + quad * 8;
#pragma unroll
    for (int nj = 0; nj < 2; ++nj) bbase[nj] = (nj * 16 + l15) * 80 + quad * 8;

    bf16x8 z8 = {0, 0, 0, 0, 0, 0, 0, 0};
#pragma unroll
    for (int ks = 0; ks < 96; ks += 32) {
        bf16x8 a[2], b[2];
#pragma unroll
        for (int mi = 0; mi < 2; ++mi) {
            a[mi] = *(const bf16x8*)(Asu + abase[mi] + ks);
            if (ks == 64 && quad >= 2) a[mi] = z8;
        }
#pragma unroll
        for (int nj = 0; nj < 2; ++nj) b[nj] = *(const bf16x8*)(Bsu + bbase[nj] + ks);
#pragma unroll
        for (int mi = 0; mi < 2; ++mi)
#pragma unroll
            for (int nj = 0; nj < 2; ++nj)
                acc[mi][nj] = __builtin_amdgcn_mfma_f32_16x16x32_bf16(a[mi], b[nj], acc[mi][nj], 0, 0, 0);
    }

#pragma unroll
    for (int mi = 0; mi < 2; ++mi)
#pragma unroll
        for (int nj = 0; nj < 2; ++nj) {
            int col = nj * 16 + l15;
            if (col < 20) {
#pragma unroll
                for (int reg = 0; reg < 4; ++reg) {
                    int row = row0 + wv * 32 + mi * 16 + quad * 4 + reg;
                    if (row < N_NODES) {
                        asd1[(size_t)row * 20 + col] = acc[mi][nj][reg];
                        if (col < 10) asrc[(size_t)row * 12 + col] = acc[mi][nj][reg];
                    }
                }
            }
        }
}

// ---------------- CSR build ----------------
// histrank: degree histogram + per-edge rank (the atomicAdd return we used to discard).
__global__ void histrank_kernel(const int* __restrict__ ei, int* __restrict__ deg,
                                int* __restrict__ rank) {
    int e = blockIdx.x * 256 + threadIdx.x;
    if (e < ETOT) rank[e] = atomicAdd(&deg[edst(ei, e)], 1);
}

__global__ __launch_bounds__(256) void scan1_kernel(const int* __restrict__ deg,
                                                    int* __restrict__ row_ptr,
                                                    int* __restrict__ bsum) {
    __shared__ int buf[256];
    int tid = threadIdx.x;
    int i = blockIdx.x * 256 + tid;
    int v = (i < N_NODES) ? deg[i] : 0;
    buf[tid] = v;
    __syncthreads();
    for (int off = 1; off < 256; off <<= 1) {
        int t = (tid >= off) ? buf[tid - off] : 0;
        __syncthreads();
        buf[tid] += t;
        __syncthreads();
    }
    if (i < N_NODES) row_ptr[i] = buf[tid] - v;
    if (tid == 255) bsum[blockIdx.x] = buf[255];
}

__global__ __launch_bounds__(256) void scan2_kernel(const int* __restrict__ bsum,
                                                    int* __restrict__ boff) {
    __shared__ int buf[256];
    int tid = threadIdx.x;
    int v = (tid < 196) ? bsum[tid] : 0;
    buf[tid] = v;
    __syncthreads();
    for (int off = 1; off < 256; off <<= 1) {
        int t = (tid >= off) ? buf[tid - off] : 0;
        __syncthreads();
        buf[tid] += t;
        __syncthreads();
    }
    if (tid < 196) boff[tid] = buf[tid] - v;
}

__global__ __launch_bounds__(256) void scan3_kernel(int* __restrict__ row_ptr,
                                                    const int* __restrict__ boff) {
    int i = blockIdx.x * 256 + threadIdx.x;
    if (i < N_NODES) row_ptr[i] = row_ptr[i] + boff[blockIdx.x];
    if (i == 0) row_ptr[N_NODES] = ETOT;
}

// atomic-free scatter: pos = row_ptr[dst] + rank[e]; one independent random 2B store.
__global__ void scatter_kernel(const int* __restrict__ ei, const int* __restrict__ row_ptr,
                               const int* __restrict__ rank, u16* __restrict__ src_arr) {
    int e = blockIdx.x * 256 + threadIdx.x;
    if (e < ETOT) {
        int d = edst(ei, e);
        src_arr[row_ptr[d] + rank[e]] = (u16)esrc(ei, e);
    }
}

// gathered per-edge registers for agg1m (one LDS slot's worth).
// Attention floats UNIONED across half-waves (r13: kept VGPR <= 64).
// half0: af = heads 0-3, af2 = heads 4-5.  half1: af = heads 6-9, af2 unused.
struct G1 {
    float4 af;
    float2 af2;
    u32x4 xv[5];             // x row (40 uints, this half's 20)
    int valid;
};

// ---------------- agg1m v5: 2-node pipeline, 2-wave blocks (r13, verified) ----------------
__global__ __launch_bounds__(128) void agg1m_kernel(const int* __restrict__ row_ptr,
                                                    const u16* __restrict__ src_arr,
                                                    const float* __restrict__ asrc,
                                                    const float* __restrict__ asd1,
                                                    const uint32* __restrict__ xbu,
                                                    u16* __restrict__ aggb16) {
    __shared__ uint32 S[2][1536];
    int tid = threadIdx.x, lane = tid & 63, wv = tid >> 6;
    int ip = blockIdx.x * 2 + wv;            // pair index
    int i0 = ip * 2, i1 = i0 + 1;
    int rs0 = row_ptr[i0], d0 = row_ptr[i0 + 1] - rs0;
    int rs1 = row_ptr[i1], d1 = row_ptr[i1 + 1] - rs1;
    uint32* xt32 = S[wv];            // [40 fp][32 slots] rotated
    uint32* wm32 = xt32 + 1280;      // [8 hp][32 slots] rotated
    int l15 = lane & 15, quad = lane >> 4;
    int slot = lane & 31, half = lane >> 5;
    u32x4 z4 = {0, 0, 0, 0};
    // head rows 10..15 (hp 5..7) stay zero forever
    if (lane < 24) *(u32x4*)(wm32 + 160 + lane * 4) = z4;
    uint32 selv = (l15 & 1) ? 0x07060302u : 0x05040100u;
    int hp = l15 >> 1;
    int pa1 = (quad * 8 + 4 * hp) & 31;
    int pa2 = (pa1 + 4) & 31;

    float dstv0[10], dstv1[10];
#pragma unroll
    for (int q = 0; q < 10; ++q) dstv0[q] = asd1[(size_t)i0 * 20 + 10 + q];
#pragma unroll
    for (int q = 0; q < 10; ++q) dstv1[q] = asd1[(size_t)i1 * 20 + 10 + q];

    auto gatherrows = [&](int s, int cnt, G1& g) {
        g.valid = slot < cnt;
        int srow = g.valid ? s : 0;
        const float* arow = asrc + (size_t)srow * 12;
        if (half == 0) {
            if (g.valid) { g.af = *(const float4*)(arow); g.af2 = *(const float2*)(arow + 4); }
        } else {
            if (g.valid) {
                float2 t0 = *(const float2*)(arow + 6);
                float2 t1 = *(const float2*)(arow + 8);
                g.af = make_float4(t0.x, t0.y, t1.x, t1.y);
            }
        }
#pragma unroll
        for (int t = 0; t < 5; ++t) {
            int c4 = 2 * t + half;
            g.xv[t] = z4;
            if (g.valid) g.xv[t] = *(const u32x4*)(xbu + (size_t)srow * 40 + c4 * 4);
        }
    };

    auto stage = [&](const G1& g, const float* dstv) {
        if (half == 0) {
            uint32 u0 = 0, u1 = 0, u2 = 0;
            if (g.valid) {
                u0 = packbf(__expf(lrelu(g.af.x + dstv[0])), __expf(lrelu(g.af.y + dstv[1])));
                u1 = packbf(__expf(lrelu(g.af.z + dstv[2])), __expf(lrelu(g.af.w + dstv[3])));
                u2 = packbf(__expf(lrelu(g.af2.x + dstv[4])), __expf(lrelu(g.af2.y + dstv[5])));
            }
            wm32[0 * 32 + (slot & 31)] = u0;
            wm32[1 * 32 + ((slot + 4) & 31)] = u1;
            wm32[2 * 32 + ((slot + 8) & 31)] = u2;
        } else {
            uint32 u3 = 0, u4 = 0;
            if (g.valid) {
                u3 = packbf(__expf(lrelu(g.af.x + dstv[6])), __expf(lrelu(g.af.y + dstv[7])));
                u4 = packbf(__expf(lrelu(g.af.z + dstv[8])), __expf(lrelu(g.af.w + dstv[9])));
            }
            wm32[3 * 32 + ((slot + 12) & 31)] = u3;
            wm32[4 * 32 + ((slot + 16) & 31)] = u4;
        }
#pragma unroll
        for (int t = 0; t < 5; ++t) {
            int c4 = 2 * t + half;
            uint32* rowp = xt32 + (4 * c4) * 32;
#pragma unroll
            for (int k = 0; k < 4; ++k)
                rowp[k * 32 + ((slot + 16 * c4 + 4 * k) & 31)] = g.xv[t][k];
        }
    };

    auto domfma = [&](f32x4* acc) {
        int arow2 = hp * 32;
        u32x4 a0 = *(const u32x4*)(wm32 + arow2 + pa1);
        u32x4 a1 = *(const u32x4*)(wm32 + arow2 + pa2);
        u32x4 au = {__builtin_amdgcn_perm(a0[1], a0[0], selv),
                    __builtin_amdgcn_perm(a0[3], a0[2], selv),
                    __builtin_amdgcn_perm(a1[1], a1[0], selv),
                    __builtin_amdgcn_perm(a1[3], a1[2], selv)};
        bf16x8 af = *(bf16x8*)&au;
#pragma unroll
        for (int nt = 0; nt < 5; ++nt) {
            int browb = (nt * 8 + hp) * 32;
            u32x4 b0 = *(const u32x4*)(xt32 + browb + pa1);
            u32x4 b1 = *(const u32x4*)(xt32 + browb + pa2);
            u32x4 bu = {__builtin_amdgcn_perm(b0[1], b0[0], selv),
                        __builtin_amdgcn_perm(b0[3], b0[2], selv),
                        __builtin_amdgcn_perm(b1[1], b1[0], selv),
                        __builtin_amdgcn_perm(b1[3], b1[2], selv)};
            bf16x8 bf = *(bf16x8*)&bu;
            acc[nt] = __builtin_amdgcn_mfma_f32_16x16x32_bf16(af, bf, acc[nt], 0, 0, 0);
        }
    };

    auto writeout = [&](int i, f32x4* acc) {
        float rden[4];
#pragma unroll
        for (int reg = 0; reg < 4; ++reg) {
            float d = __shfl(acc[4][reg], (lane & 48) | 14, 64);
            rden[reg] = __builtin_amdgcn_rcpf(d);
        }
        size_t nb = (size_t)i * 80 + l15;
#pragma unroll
        for (int reg = 0; reg < 4; ++reg) {
            int head = quad * 4 + reg;
            if (head < 10) {
                u16* hpn = aggb16 + (size_t)head * (size_t)PL40 * 2 + nb;
#pragma unroll
                for (int nt = 0; nt < 5; ++nt) {
                    float v = acc[nt][reg] * rden[reg];
                    u16 b = f2bfbits(v);
                    if (nt == 4 && l15 >= 14) b = 0;   // feats 78,79 -> 0
                    hpn[nt * 16] = b;
                }
            }
        }
    };

    f32x4 acc0[5], acc1[5];
#pragma unroll
    for (int nt = 0; nt < 5; ++nt) { acc0[nt] = (f32x4){0.f,0.f,0.f,0.f}; acc1[nt] = (f32x4){0.f,0.f,0.f,0.f}; }

    if (d0 <= 32 && d1 <= 32) {
        // fast pipelined path (covers ~99.96% of pairs)
        int s0 = (int)src_arr[rs0 + slot];
        int s1 = (int)src_arr[rs1 + slot];
        G1 g0, g1;
        gatherrows(s0, d0, g0);
        stage(g0, dstv0);              // vmcnt waits only g0's loads
        gatherrows(s1, d1, g1);        // issue node1 gathers (s1 long since arrived)
        __builtin_amdgcn_wave_barrier();
        domfma(acc0);                  // LDS frags + MFMA, overlaps g1 flight
        writeout(i0, acc0);            // global stores + shfl, overlaps g1 flight
        __builtin_amdgcn_wave_barrier();
        stage(g1, dstv1);              // by now most of g1 latency is hidden
        __builtin_amdgcn_wave_barrier();
        domfma(acc1);
        writeout(i1, acc1);
    } else {
        // serial fallback, same helpers
        int rss[2] = {rs0, rs1}, dd[2] = {d0, d1}, ii[2] = {i0, i1};
#pragma unroll
        for (int n = 0; n < 2; ++n) {
            f32x4* acc = (n == 0) ? acc0 : acc1;
            const float* dv = (n == 0) ? dstv0 : dstv1;
            for (int base = 0; base < dd[n]; base += 32) {
                int cnt = min(dd[n] - base, 32);
                int s = (int)src_arr[rss[n] + base + slot];
                G1 g;
                gatherrows(s, cnt, g);
                stage(g, dv);
                __builtin_amdgcn_wave_barrier();
                domfma(acc);
                __builtin_amdgcn_wave_barrier();
            }
            writeout(ii[n], acc);
        }
    }
}

// ---------------- gemmf v6: 128-row blocks + B2 fragments hoisted to registers ----------------
// r17 post-mortem: v5 halved B STAGING but not B LDS READS (each rt re-reads B1/B2 frags).
// Per head per wave: 90 ds_read_b128 (~1080cy) vs ~374cy MFMA -> DS-read-issue bound.
// v6: B2 frags (24 reads, the largest stream) loaded ONCE per head into b2f[8][3]
// registers (statically indexed, 96 VGPR) and reused across both rt halves:
// 90 -> 66 reads/head/wave (-27%). VGPR ~200, but occupancy stays LDS-bound at
// 2 blocks x 4 waves = 8 waves/CU, so the VGPR increase is free.
__global__ __launch_bounds__(256) void gemmf_kernel(const uint32* __restrict__ aggb,
                                                    const uint32* __restrict__ w1p,
                                                    const uint32* __restrict__ w2p,
                                                    const float* __restrict__ b1,
                                                    const float* __restrict__ w2as,
                                                    const float* __restrict__ w2ad,
                                                    u16* __restrict__ h2,
                                                    float* __restrict__ as2,
                                                    float* __restrict__ ad2) {
    __shared__ uint32 As[5128];     // aggb[h] 128 rows (5120 dw + 8 pad)
    __shared__ uint32 Bs1[3208];    // w1p[h] (3200 dw + 8 pad)
    __shared__ uint32 Bs2[5128];    // w2p[h] (5120 dw + 8 pad)
    __shared__ uint32 C1s[2568];    // relu(gemm1) bf16 [64][80], reused per rt (+8 pad)
    int tid = threadIdx.x, lane = tid & 63, wv = tid >> 6;
    int row0 = blockIdx.x * 128;
    int l15 = lane & 15, quad = lane >> 4;
    const u16* Asu = (const u16*)As;
    const u16* B1u = (const u16*)Bs1;
    const u16* B2u = (const u16*)Bs2;
    const u16* C1u = (const u16*)C1s;
    u16* Cw = (u16*)C1s;

    f32x4 acc2[2][8];
#pragma unroll
    for (int rt = 0; rt < 2; ++rt)
#pragma unroll
        for (int nj = 0; nj < 8; ++nj) acc2[rt][nj] = (f32x4){0.f, 0.f, 0.f, 0.f};
    float s2p[2][4] = {}, d2p[2][4] = {};

    int abase64 = (wv * 16 + l15) * 80 + quad * 8;   // intra-rt row offset (A frag / C1 frag)
    int b1base[5];
#pragma unroll
    for (int nj = 0; nj < 5; ++nj) b1base[nj] = (nj * 16 + l15) * 80 + quad * 8;
    int b2base[8];
#pragma unroll
    for (int nj = 0; nj < 8; ++nj) b2base[nj] = (nj * 16 + l15) * 80 + quad * 8;
    bf16x8 z8 = {0, 0, 0, 0, 0, 0, 0, 0};
    int rl0 = wv * 16 + quad * 4;

    auto stageA = [&](int h) {
        const uint32* aplane = aggb + (size_t)h * PL40 + (size_t)row0 * 40;
        for (int t = wv; t < 20; t += 4)
            cp16(As + t * 256, aplane + t * 256, lane);
    };
    auto stageB = [&](int h) {
        const uint32* w1pl = w1p + (size_t)h * 3200;
        const uint32* w2pl = w2p + (size_t)h * 5120;
        // Bs1: 3200 dwords = 12 full tiles + one half-masked tile (lanes < 32)
        int tw0 = wv * 3, tw1 = (wv == 3) ? 12 : wv * 3 + 3;
        for (int t = tw0; t < tw1; ++t)
            cp16(Bs1 + t * 256, w1pl + t * 256, lane);
        if (wv == 3 && lane < 32)
            cp16(Bs1 + 12 * 256, w1pl + 12 * 256, lane);
#pragma unroll
        for (int t = 0; t < 5; ++t)
            cp16(Bs2 + (wv * 5 + t) * 256, w2pl + (wv * 5 + t) * 256, lane);
    };

    stageA(0);
    stageB(0);
    for (int h = 0; h < 10; ++h) {
        __syncthreads();               // staging for head h complete
        // hoist B2 fragments to registers ONCE per head (reused across both rt)
        bf16x8 b2f[8][3];
#pragma unroll
        for (int nj = 0; nj < 8; ++nj)
#pragma unroll
            for (int k3 = 0; k3 < 3; ++k3)
                b2f[nj][k3] = *(const bf16x8*)(B2u + b2base[nj] + k3 * 32);
#pragma unroll
        for (int rt = 0; rt < 2; ++rt) {
            int abase = rt * 64 * 80 + abase64;      // u16 offset into 128-row As
            // gemm1: C1 = aggb[h][rt*64..] @ w1p[h]
            f32x4 acc1[5];
#pragma unroll
            for (int nj = 0; nj < 5; ++nj) acc1[nj] = (f32x4){0.f, 0.f, 0.f, 0.f};
#pragma unroll
            for (int ks = 0; ks < 96; ks += 32) {
                bf16x8 a = *(const bf16x8*)(Asu + abase + ks);
                if (ks == 64 && quad >= 2) a = z8;
#pragma unroll
                for (int nj = 0; nj < 5; ++nj) {
                    bf16x8 b = *(const bf16x8*)(B1u + b1base[nj] + ks);
                    acc1[nj] = __builtin_amdgcn_mfma_f32_16x16x32_bf16(a, b, acc1[nj], 0, 0, 0);
                }
            }
            // epilogue: bias+relu -> C1s (wave-local rows), accumulate as2/ad2 partials
#pragma unroll
            for (int nj = 0; nj < 5; ++nj) {
                int col = nj * 16 + l15;
                if (col < 78) {
                    int gc = h * 78 + col;
                    float bia = b1[gc], was = w2as[gc], wad = w2ad[gc];
#pragma unroll
                    for (int reg = 0; reg < 4; ++reg) {
                        float v = fmaxf(acc1[nj][reg] + bia, 0.f);
                        Cw[(rl0 + reg) * 80 + col] = f2bfbits(v);
                        s2p[rt][reg] = fmaf(v, was, s2p[rt][reg]);
                        d2p[rt][reg] = fmaf(v, wad, d2p[rt][reg]);
                    }
                } else {
#pragma unroll
                    for (int reg = 0; reg < 4; ++reg) Cw[(rl0 + reg) * 80 + col] = 0;
                }
            }
            __builtin_amdgcn_wave_barrier();
            // gemm2 accumulate: acc2[rt] += relu(C1) @ w2p[h] (B from registers)
#pragma unroll
            for (int k3 = 0; k3 < 3; ++k3) {
                bf16x8 a = *(const bf16x8*)(C1u + abase64 + k3 * 32);
                if (k3 == 2 && quad >= 2) a = z8;
#pragma unroll
                for (int nj = 0; nj < 8; ++nj)
                    acc2[rt][nj] = __builtin_amdgcn_mfma_f32_16x16x32_bf16(a, b2f[nj][k3], acc2[rt][nj], 0, 0, 0);
            }
            __builtin_amdgcn_wave_barrier();   // C1s reuse ordering (same wave)
        }
        __syncthreads();               // all waves done reading As/Bs1/Bs2
        if (h < 9) { stageA(h + 1); stageB(h + 1); }
    }

    // write h2 (bf16)
#pragma unroll
    for (int rt = 0; rt < 2; ++rt)
#pragma unroll
        for (int nj = 0; nj < 8; ++nj) {
            int col = nj * 16 + l15;
#pragma unroll
            for (int reg = 0; reg < 4; ++reg) {
                int r = row0 + rt * 64 + rl0 + reg;
                if (r < N_NODES) h2[(size_t)r * OUT2 + col] = f2bfbits(acc2[rt][nj][reg]);
            }
        }
    // as2/ad2: reduce over the 16 l15 lanes (cols), write once per rt
#pragma unroll
    for (int off = 1; off < 16; off <<= 1)
#pragma unroll
        for (int rt = 0; rt < 2; ++rt)
#pragma unroll
            for (int reg = 0; reg < 4; ++reg) {
                s2p[rt][reg] += __shfl_xor(s2p[rt][reg], off, 64);
                d2p[rt][reg] += __shfl_xor(d2p[rt][reg], off, 64);
            }
    if (l15 == 0) {
#pragma unroll
        for (int rt = 0; rt < 2; ++rt)
#pragma unroll
            for (int reg = 0; reg < 4; ++reg) {
                int r = row0 + rt * 64 + rl0 + reg;
                if (r < N_NODES) {
                    as2[r] = s2p[rt][reg];
                    ad2[r] = d2p[rt][reg];
                }
            }
    }
}

// ---------------- layer-2 aggregation + pool (fused expw2, 8-deep gather ILP, block max pre-reduce) ----------------
__global__ __launch_bounds__(256) void agg2_kernel(const int* __restrict__ row_ptr,
                                                   const u16* __restrict__ src_arr,
                                                   const float* __restrict__ as2,
                                                   const float* __restrict__ ad2,
                                                   const uint32* __restrict__ h2u,
                                                   const float* __restrict__ b2,
                                                   const int* __restrict__ batch,
                                                   float* __restrict__ pooled) {
    __shared__ float w_sh[4][64];
    __shared__ int src_sh[4][64];
    __shared__ float red[4][128];
    __shared__ int gsh[4];
    int tid = threadIdx.x, lane = tid & 63, wv = tid >> 6;
    int i = blockIdx.x * 4 + wv;
    int rs = row_ptr[i], deg = row_ptr[i + 1] - rs;
    float ad2i = ad2[i];   // wave-uniform dst projection (expw2 fused)

    f32x2 acc = {0.f, 0.f};
    float den = 0.f;
    if (deg <= 64) {
        if (lane < deg) {
            int s = (int)src_arr[rs + lane];
            float w = __expf(lrelu(as2[s] + ad2i));
            den = w;
            w_sh[wv][lane] = w;
            src_sh[wv][lane] = s;
        }
        __builtin_amdgcn_wave_barrier();
#pragma unroll
        for (int off = 1; off < 64; off <<= 1) den += __shfl_xor(den, off, 64);
        float rden = __builtin_amdgcn_rcpf(den);
        int cnt = deg, eix = 0;
        for (; eix + 7 < cnt; eix += 8) {
            int ss[8];
            float ww[8];
            uint32 uu[8];
#pragma unroll
            for (int q = 0; q < 8; ++q) {
                ss[q] = src_sh[wv][eix + q];
                ww[q] = w_sh[wv][eix + q];
            }
#pragma unroll
            for (int q = 0; q < 8; ++q) uu[q] = h2u[(size_t)ss[q] * 64 + lane];
#pragma unroll
            for (int q = 0; q < 8; ++q) acc = ww[q] * bf2(uu[q]) + acc;
        }
        for (; eix < cnt; ++eix) {
            int s0 = src_sh[wv][eix];
            float w0 = w_sh[wv][eix];
            uint32 u0 = h2u[(size_t)s0 * 64 + lane];
            acc = w0 * bf2(u0) + acc;
        }
        acc *= rden;
    } else {
        for (int eix = lane; eix < deg; eix += 64)
            den += __expf(lrelu(as2[(int)src_arr[rs + eix]] + ad2i));
#pragma unroll
        for (int off = 1; off < 64; off <<= 1) den += __shfl_xor(den, off, 64);
        float rden = __builtin_amdgcn_rcpf(den);
        for (int base = 0; base < deg; base += 64) {
            int cnt = min(deg - base, 64);
            if (lane < cnt) {
                int s = (int)src_arr[rs + base + lane];
                w_sh[wv][lane] = __expf(lrelu(as2[s] + ad2i));
                src_sh[wv][lane] = s;
            }
            __builtin_amdgcn_wave_barrier();
            int eix = 0;
            for (; eix + 7 < cnt; eix += 8) {
                int ss[8];
                float ww[8];
                uint32 uu[8];
#pragma unroll
                for (int q = 0; q < 8; ++q) {
                    ss[q] = src_sh[wv][eix + q];
                    ww[q] = w_sh[wv][eix + q];
                }
#pragma unroll
                for (int q = 0; q < 8; ++q) uu[q] = h2u[(size_t)ss[q] * 64 + lane];
#pragma unroll
                for (int q = 0; q < 8; ++q) acc = ww[q] * bf2(uu[q]) + acc;
            }
            for (; eix < cnt; ++eix) {
                int s0 = src_sh[wv][eix];
                float w0 = w_sh[wv][eix];
                uint32 u0 = h2u[(size_t)s0 * 64 + lane];
                acc = w0 * bf2(u0) + acc;
            }
            __builtin_amdgcn_wave_barrier();
        }
        acc *= rden;
    }
    float2 bv = ((const float2*)b2)[lane];
    float v0 = fmaxf(acc.x + bv.x, 0.f);
    float v1 = fmaxf(acc.y + bv.y, 0.f);
    int g = batch[i];
    // block-level max pre-reduction: batch is sorted, so the block's 4 nodes usually
    // share one graph -> ~4x fewer device-scope atomics.
    red[wv][2 * lane] = v0;
    red[wv][2 * lane + 1] = v1;
    if (lane == 0) gsh[wv] = g;
    __syncthreads();
    bool leader = true;
#pragma unroll
    for (int w2i = 0; w2i < 3; ++w2i)
        if (w2i < wv && gsh[w2i] == g) leader = false;
    if (leader) {
        float m0 = v0, m1 = v1;
#pragma unroll
        for (int w2i = 1; w2i < 4; ++w2i) {
            if (w2i > wv && gsh[w2i] == g) {
                m0 = fmaxf(m0, red[w2i][2 * lane]);
                m1 = fmaxf(m1, red[w2i][2 * lane + 1]);
            }
        }
        atomicMax((int*)&pooled[g * OUT2 + 2 * lane], __float_as_int(m0));
        atomicMax((int*)&pooled[g * OUT2 + 2 * lane + 1], __float_as_int(m1));
    }
}

// ---------------- final FC + relu ----------------
__global__ __launch_bounds__(128) void fc_kernel(const float* __restrict__ pooled,
                                                 const float* __restrict__ fcW,
                                                 const float* __restrict__ fcb,
                                                 float* __restrict__ out) {
    int g = blockIdx.x, tid = threadIdx.x;
    __shared__ float p[128];
    p[tid] = pooled[g * OUT2 + tid];
    __syncthreads();
    float acc = fcb[tid];
    for (int k = 0; k < 128; ++k) acc = fmaf(p[k], fcW[k * OUT2 + tid], acc);
    out[g * OUT2 + tid] = fmaxf(acc, 0.f);
}

extern "C" void kernel_launch(void* const* d_in, const int* in_sizes, int n_in,
                              void* d_out, int out_size, void* d_ws, size_t ws_size,
                              hipStream_t stream) {
    const float* x      = (const float*)d_in[0];
    const int*   ei     = (const int*)d_in[1];
    const int*   batch  = (const int*)d_in[2];
    const float* W1     = (const float*)d_in[4];
    const float* a_src1 = (const float*)d_in[5];
    const float* a_dst1 = (const float*)d_in[6];
    const float* b1     = (const float*)d_in[7];
    const float* W2     = (const float*)d_in[8];
    const float* a_src2 = (const float*)d_in[9];
    const float* a_dst2 = (const float*)d_in[10];
    const float* b2     = (const float*)d_in[11];
    const float* fcW    = (const float*)d_in[12];
    const float* fcb    = (const float*)d_in[13];
    float* out = (float*)d_out;

    size_t off = 0;
    char* base = (char*)d_ws;
    auto alloc = [&](size_t bytes) -> void* {
        void* p = base + off;
        off += (bytes + 255) & ~(size_t)255;
        return p;
    };
    uint32* aggb  = (uint32*)alloc(PL40 * 10 * 4);            // [10][NP][40u]
    u16* h2arena  = (u16*)alloc((size_t)N_NODES * OUT2 * 2);  // h2; xbp aliases early
    u16* h2   = h2arena;
    u16* xbp  = h2arena;                                      // [NP][80 u16] = 8.0 MB < 12.8 MB ✓
    float* asd1 = (float*)alloc((size_t)N_NODES * 20 * 4);
    float* asrc = (float*)alloc((size_t)N_NODES * 12 * 4);    // compact src projections
    float* as2  = (float*)alloc((size_t)N_NODES * 4);
    float* ad2  = (float*)alloc((size_t)N_NODES * 4);
    u16* w1p    = (u16*)alloc((size_t)(10 * 80 * 80) * 2 + 1024);  // + stage slack
    u16* w2p    = (u16*)alloc((size_t)(10 * 128 * 80) * 2);
    u16* VAT    = (u16*)alloc((size_t)32 * 80 * 2);
    float* w2as = (float*)alloc((size_t)D1 * 4);
    float* w2ad = (float*)alloc((size_t)D1 * 4);
    float* pooled = (float*)alloc((size_t)NGRAPH * OUT2 * 4);
    int* deg     = (int*)alloc((size_t)N_NODES * 4);
    int* row_ptr = (int*)alloc((size_t)(N_NODES + 1) * 4);
    int* rank    = (int*)alloc((size_t)ETOT * 4);
    u16* src_arr = (u16*)alloc((size_t)ETOT * 2);
    int* bsum    = (int*)alloc(196 * 4);
    int* boff    = (int*)alloc(196 * 4);

    hipMemsetAsync(deg, 0, (size_t)N_NODES * 4, stream);
    hipMemsetAsync(pooled, 0, (size_t)NGRAPH * OUT2 * 4, stream);

    prep_kernel<<<2048, 256, 0, stream>>>(x, W1, W2, xbp, w1p, w2p);
    prep2_kernel<<<8, 256, 0, stream>>>(W1, a_src1, a_dst1, W2, a_src2, a_dst2,
                                        VAT, w2as, w2ad);
    alphas1x_kernel<<<391, 256, 0, stream>>>((const uint32*)xbp, (const uint32*)VAT,
                                             asd1, asrc);
    histrank_kernel<<<(ETOT + 255) / 256, 256, 0, stream>>>(ei, deg, rank);
    scan1_kernel<<<196, 256, 0, stream>>>(deg, row_ptr, bsum);
    scan2_kernel<<<1, 256, 0, stream>>>(bsum, boff);
    scan3_kernel<<<196, 256, 0, stream>>>(row_ptr, boff);
    scatter_kernel<<<(ETOT + 255) / 256, 256, 0, stream>>>(ei, row_ptr, rank, src_arr);
    agg1m_kernel<<<N_NODES / 4, 128, 0, stream>>>(row_ptr, src_arr, asrc, asd1,
                                                  (const uint32*)xbp, (u16*)aggb);
    gemmf_kernel<<<NP / 128, 256, 0, stream>>>(aggb, (const uint32*)w1p, (const uint32*)w2p,
                                               b1, w2as, w2ad, h2, as2, ad2);
    agg2_kernel<<<N_NODES / 4, 256, 0, stream>>>(row_ptr, src_arr, as2, ad2,
                                                 (const uint32*)h2, b2, batch, pooled);
    fc_kernel<<<NGRAPH, 128, 0, stream>>>(pooled, fcW, fcb, out);
}

// Round 19
// 307.458 us; speedup vs baseline: 1.0867x; 1.0867x over previous
//
#include <hip/hip_runtime.h>
#include <hip/hip_bf16.h>
#include <stdint.h>

typedef unsigned int uint32;
typedef unsigned short u16;
typedef __attribute__((ext_vector_type(8))) short bf16x8;
typedef __attribute__((ext_vector_type(4))) float f32x4;
typedef __attribute__((ext_vector_type(2))) float f32x2;
typedef uint32 u32x4 __attribute__((ext_vector_type(4)));

#define N_NODES 50000
#define NP      50048                 // padded row count (391*128)
#define N_EDGES 800000
#define ETOT    (N_EDGES + N_NODES)
#define F_INN   78
#define H1      10
#define D1      780
#define OUT2    128
#define NGRAPH  512
#define NEG_SLOPE 0.2f
#define PL40    ((size_t)NP * 40)     // uints per padded head-plane

__device__ __forceinline__ float lrelu(float v) { return v > 0.f ? v : NEG_SLOPE * v; }
__device__ __forceinline__ u16 f2bfbits(float f) {
    return __bfloat16_as_ushort(__float2bfloat16(f));
}
__device__ __forceinline__ uint32 packbf(float lo, float hi) {
    return (uint32)f2bfbits(lo) | ((uint32)f2bfbits(hi) << 16);
}
__device__ __forceinline__ f32x2 bf2(uint32 u) {
    __hip_bfloat162 b = *reinterpret_cast<__hip_bfloat162*>(&u);
    float2 t = __bfloat1622float2(b);
    return (f32x2){t.x, t.y};
}
__device__ __forceinline__ int esrc(const int* ei, int e) { return e < N_EDGES ? ei[e] : e - N_EDGES; }
__device__ __forceinline__ int edst(const int* ei, int e) { return e < N_EDGES ? ei[N_EDGES + e] : e - N_EDGES; }

// async global->LDS 16B per lane: lane i moves g[lane*16B] -> lds_base + lane*16B
typedef __attribute__((address_space(1))) const uint32 guint;
typedef __attribute__((address_space(3))) uint32 luint;
__device__ __forceinline__ void cp16(uint32* lds, const uint32* g, int lane) {
    __builtin_amdgcn_global_load_lds((guint*)(g + lane * 4), (luint*)lds, 16, 0, 0);
}

// ---------------- prep: xbp [NP][80 u16], w1p [10][80][80 u16], w2p [10][128][80 u16] ----------------
// NOTE: xbp feat 78 is set to bf16(1.0): agg1m uses that column to get the softmax
// denominator for free (C[h][78] = sum of weights). alphas1x is unaffected (VAT col 78 = 0),
// gemmf is unaffected (w1p rows 78/79 = 0).
#define NXP (N_NODES * 80)
__global__ __launch_bounds__(256) void prep_kernel(const float* __restrict__ x,
                                                   const float* __restrict__ W1,
                                                   const float* __restrict__ W2,
                                                   u16* __restrict__ xbp,
                                                   u16* __restrict__ w1p,
                                                   u16* __restrict__ w2p) {
    const int total = NXP + 10 * 80 * 80 + 10 * 128 * 80;
    for (int id = blockIdx.x * 256 + threadIdx.x; id < total; id += gridDim.x * 256) {
        if (id < NXP) {
            int n = id / 80, k = id - n * 80;
            xbp[id] = (k < 78) ? f2bfbits(x[n * 78 + k]) : ((k == 78) ? (u16)0x3F80 : (u16)0);
        } else if (id < NXP + 64000) {
            int t = id - NXP;
            int h = t / 6400, r = t - h * 6400;
            int n = r / 80, k = r - n * 80;
            w1p[t] = (n < 78 && k < 78) ? f2bfbits(W1[k * D1 + h * 78 + n]) : (u16)0;
        } else {
            int t = id - NXP - 64000;
            int h = t / 10240, r = t - h * 10240;
            int n = r / 80, k = r - n * 80;
            w2p[t] = (k < 78) ? f2bfbits(W2[(h * 78 + k) * OUT2 + n]) : (u16)0;
        }
    }
}

// ---------------- prep2: VAT [32][80 u16] padded + w2as/w2ad ----------------
__global__ __launch_bounds__(256) void prep2_kernel(const float* __restrict__ W1,
                                                    const float* __restrict__ a_src1,
                                                    const float* __restrict__ a_dst1,
                                                    const float* __restrict__ W2,
                                                    const float* __restrict__ a_src2,
                                                    const float* __restrict__ a_dst2,
                                                    u16* __restrict__ VAT,
                                                    float* __restrict__ w2as,
                                                    float* __restrict__ w2ad) {
    int gid = blockIdx.x * 256 + threadIdx.x;
    int gs = gridDim.x * 256;
    for (int idx = gid; idx < 32 * 80; idx += gs) {
        int j = idx / 80, k = idx - j * 80;
        float s = 0.f;
        if (j < 20 && k < 78) {
            int h = (j < 10) ? j : j - 10;
            const float* vec = ((j < 10) ? a_src1 : a_dst1) + h * F_INN;
            const float* wrow = W1 + k * D1 + h * F_INN;
            for (int f = 0; f < F_INN; ++f) s = fmaf(wrow[f], vec[f], s);
            VAT[idx] = f2bfbits(s);
        } else {
            VAT[idx] = 0;
        }
    }
    for (int c = gid; c < D1; c += gs) {
        const float* r0 = W2 + (size_t)c * OUT2;
        float s = 0.f, d = 0.f;
        for (int j = 0; j < OUT2; ++j) {
            s = fmaf(r0[j], a_src2[j], s);
            d = fmaf(r0[j], a_dst2[j], d);
        }
        w2as[c] = s;
        w2ad[c] = d;
    }
}

// ---------------- alphas1x: xbp[128 rows] @ VAT^T -> asd1[N][20] + compact asrc[N][12] ----------------
__global__ __launch_bounds__(256) void alphas1x_kernel(const uint32* __restrict__ xbu,
                                                       const uint32* __restrict__ vatu,
                                                       float* __restrict__ asd1,
                                                       float* __restrict__ asrc) {
    __shared__ uint32 As[5136];
    __shared__ uint32 Bs[1296];
    int tid = threadIdx.x, lane = tid & 63, wv = tid >> 6;
    int row0 = blockIdx.x * 128;
    const uint32* aplane = xbu + (size_t)row0 * 40;

#pragma unroll
    for (int t = 0; t < 5; ++t)
        cp16(As + wv * 1280 + t * 256, aplane + wv * 1280 + t * 256, lane);
    if (wv == 0) {
#pragma unroll
        for (int t = 0; t < 5; ++t)
            cp16(Bs + t * 256, vatu + t * 256, lane);
    }
    __syncthreads();

    int l15 = lane & 15, quad = lane >> 4;
    const u16* Asu = (const u16*)As;
    const u16* Bsu = (const u16*)Bs;
    f32x4 acc[2][2];
#pragma unroll
    for (int mi = 0; mi < 2; ++mi)
#pragma unroll
        for (int nj = 0; nj < 2; ++nj) acc[mi][nj] = (f32x4){0.f, 0.f, 0.f, 0.f};

    int abase[2], bbase[2];
#pragma unroll
    for (int mi = 0; mi < 2; ++mi) abase[mi] = (wv * 32 + mi * 16 + l15) * 80 + quad * 8;
#pragma unroll
    for (int nj = 0; nj < 2; ++nj) bbase[nj] = (nj * 16 + l15) * 80 + quad * 8;

    bf16x8 z8 = {0, 0, 0, 0, 0, 0, 0, 0};
#pragma unroll
    for (int ks = 0; ks < 96; ks += 32) {
        bf16x8 a[2], b[2];
#pragma unroll
        for (int mi = 0; mi < 2; ++mi) {
            a[mi] = *(const bf16x8*)(Asu + abase[mi] + ks);
            if (ks == 64 && quad >= 2) a[mi] = z8;
        }
#pragma unroll
        for (int nj = 0; nj < 2; ++nj) b[nj] = *(const bf16x8*)(Bsu + bbase[nj] + ks);
#pragma unroll
        for (int mi = 0; mi < 2; ++mi)
#pragma unroll
            for (int nj = 0; nj < 2; ++nj)
                acc[mi][nj] = __builtin_amdgcn_mfma_f32_16x16x32_bf16(a[mi], b[nj], acc[mi][nj], 0, 0, 0);
    }

#pragma unroll
    for (int mi = 0; mi < 2; ++mi)
#pragma unroll
        for (int nj = 0; nj < 2; ++nj) {
            int col = nj * 16 + l15;
            if (col < 20) {
#pragma unroll
                for (int reg = 0; reg < 4; ++reg) {
                    int row = row0 + wv * 32 + mi * 16 + quad * 4 + reg;
                    if (row < N_NODES) {
                        asd1[(size_t)row * 20 + col] = acc[mi][nj][reg];
                        if (col < 10) asrc[(size_t)row * 12 + col] = acc[mi][nj][reg];
                    }
                }
            }
        }
}

// ---------------- CSR build ----------------
// histrank: degree histogram + per-edge rank (the atomicAdd return we used to discard).
__global__ void histrank_kernel(const int* __restrict__ ei, int* __restrict__ deg,
                                int* __restrict__ rank) {
    int e = blockIdx.x * 256 + threadIdx.x;
    if (e < ETOT) rank[e] = atomicAdd(&deg[edst(ei, e)], 1);
}

__global__ __launch_bounds__(256) void scan1_kernel(const int* __restrict__ deg,
                                                    int* __restrict__ row_ptr,
                                                    int* __restrict__ bsum) {
    __shared__ int buf[256];
    int tid = threadIdx.x;
    int i = blockIdx.x * 256 + tid;
    int v = (i < N_NODES) ? deg[i] : 0;
    buf[tid] = v;
    __syncthreads();
    for (int off = 1; off < 256; off <<= 1) {
        int t = (tid >= off) ? buf[tid - off] : 0;
        __syncthreads();
        buf[tid] += t;
        __syncthreads();
    }
    if (i < N_NODES) row_ptr[i] = buf[tid] - v;
    if (tid == 255) bsum[blockIdx.x] = buf[255];
}

__global__ __launch_bounds__(256) void scan2_kernel(const int* __restrict__ bsum,
                                                    int* __restrict__ boff) {
    __shared__ int buf[256];
    int tid = threadIdx.x;
    int v = (tid < 196) ? bsum[tid] : 0;
    buf[tid] = v;
    __syncthreads();
    for (int off = 1; off < 256; off <<= 1) {
        int t = (tid >= off) ? buf[tid - off] : 0;
        __syncthreads();
        buf[tid] += t;
        __syncthreads();
    }
    if (tid < 196) boff[tid] = buf[tid] - v;
}

__global__ __launch_bounds__(256) void scan3_kernel(int* __restrict__ row_ptr,
                                                    const int* __restrict__ boff) {
    int i = blockIdx.x * 256 + threadIdx.x;
    if (i < N_NODES) row_ptr[i] = row_ptr[i] + boff[blockIdx.x];
    if (i == 0) row_ptr[N_NODES] = ETOT;
}

// atomic-free scatter: pos = row_ptr[dst] + rank[e]; one independent random 2B store.
__global__ void scatter_kernel(const int* __restrict__ ei, const int* __restrict__ row_ptr,
                               const int* __restrict__ rank, u16* __restrict__ src_arr) {
    int e = blockIdx.x * 256 + threadIdx.x;
    if (e < ETOT) {
        int d = edst(ei, e);
        src_arr[row_ptr[d] + rank[e]] = (u16)esrc(ei, e);
    }
}

// gathered per-edge registers for agg1m (one LDS slot's worth).
// Attention floats UNIONED across half-waves (r13: kept VGPR <= 64).
// half0: af = heads 0-3, af2 = heads 4-5.  half1: af = heads 6-9, af2 unused.
struct G1 {
    float4 af;
    float2 af2;
    u32x4 xv[5];             // x row (40 uints, this half's 20)
    int valid;
};

// ---------------- agg1m v5: 2-node pipeline, 2-wave blocks (r13, verified) ----------------
__global__ __launch_bounds__(128) void agg1m_kernel(const int* __restrict__ row_ptr,
                                                    const u16* __restrict__ src_arr,
                                                    const float* __restrict__ asrc,
                                                    const float* __restrict__ asd1,
                                                    const uint32* __restrict__ xbu,
                                                    u16* __restrict__ aggb16) {
    __shared__ uint32 S[2][1536];
    int tid = threadIdx.x, lane = tid & 63, wv = tid >> 6;
    int ip = blockIdx.x * 2 + wv;            // pair index
    int i0 = ip * 2, i1 = i0 + 1;
    int rs0 = row_ptr[i0], d0 = row_ptr[i0 + 1] - rs0;
    int rs1 = row_ptr[i1], d1 = row_ptr[i1 + 1] - rs1;
    uint32* xt32 = S[wv];            // [40 fp][32 slots] rotated
    uint32* wm32 = xt32 + 1280;      // [8 hp][32 slots] rotated
    int l15 = lane & 15, quad = lane >> 4;
    int slot = lane & 31, half = lane >> 5;
    u32x4 z4 = {0, 0, 0, 0};
    // head rows 10..15 (hp 5..7) stay zero forever
    if (lane < 24) *(u32x4*)(wm32 + 160 + lane * 4) = z4;
    uint32 selv = (l15 & 1) ? 0x07060302u : 0x05040100u;
    int hp = l15 >> 1;
    int pa1 = (quad * 8 + 4 * hp) & 31;
    int pa2 = (pa1 + 4) & 31;

    float dstv0[10], dstv1[10];
#pragma unroll
    for (int q = 0; q < 10; ++q) dstv0[q] = asd1[(size_t)i0 * 20 + 10 + q];
#pragma unroll
    for (int q = 0; q < 10; ++q) dstv1[q] = asd1[(size_t)i1 * 20 + 10 + q];

    auto gatherrows = [&](int s, int cnt, G1& g) {
        g.valid = slot < cnt;
        int srow = g.valid ? s : 0;
        const float* arow = asrc + (size_t)srow * 12;
        if (half == 0) {
            if (g.valid) { g.af = *(const float4*)(arow); g.af2 = *(const float2*)(arow + 4); }
        } else {
            if (g.valid) {
                float2 t0 = *(const float2*)(arow + 6);
                float2 t1 = *(const float2*)(arow + 8);
                g.af = make_float4(t0.x, t0.y, t1.x, t1.y);
            }
        }
#pragma unroll
        for (int t = 0; t < 5; ++t) {
            int c4 = 2 * t + half;
            g.xv[t] = z4;
            if (g.valid) g.xv[t] = *(const u32x4*)(xbu + (size_t)srow * 40 + c4 * 4);
        }
    };

    auto stage = [&](const G1& g, const float* dstv) {
        if (half == 0) {
            uint32 u0 = 0, u1 = 0, u2 = 0;
            if (g.valid) {
                u0 = packbf(__expf(lrelu(g.af.x + dstv[0])), __expf(lrelu(g.af.y + dstv[1])));
                u1 = packbf(__expf(lrelu(g.af.z + dstv[2])), __expf(lrelu(g.af.w + dstv[3])));
                u2 = packbf(__expf(lrelu(g.af2.x + dstv[4])), __expf(lrelu(g.af2.y + dstv[5])));
            }
            wm32[0 * 32 + (slot & 31)] = u0;
            wm32[1 * 32 + ((slot + 4) & 31)] = u1;
            wm32[2 * 32 + ((slot + 8) & 31)] = u2;
        } else {
            uint32 u3 = 0, u4 = 0;
            if (g.valid) {
                u3 = packbf(__expf(lrelu(g.af.x + dstv[6])), __expf(lrelu(g.af.y + dstv[7])));
                u4 = packbf(__expf(lrelu(g.af.z + dstv[8])), __expf(lrelu(g.af.w + dstv[9])));
            }
            wm32[3 * 32 + ((slot + 12) & 31)] = u3;
            wm32[4 * 32 + ((slot + 16) & 31)] = u4;
        }
#pragma unroll
        for (int t = 0; t < 5; ++t) {
            int c4 = 2 * t + half;
            uint32* rowp = xt32 + (4 * c4) * 32;
#pragma unroll
            for (int k = 0; k < 4; ++k)
                rowp[k * 32 + ((slot + 16 * c4 + 4 * k) & 31)] = g.xv[t][k];
        }
    };

    auto domfma = [&](f32x4* acc) {
        int arow2 = hp * 32;
        u32x4 a0 = *(const u32x4*)(wm32 + arow2 + pa1);
        u32x4 a1 = *(const u32x4*)(wm32 + arow2 + pa2);
        u32x4 au = {__builtin_amdgcn_perm(a0[1], a0[0], selv),
                    __builtin_amdgcn_perm(a0[3], a0[2], selv),
                    __builtin_amdgcn_perm(a1[1], a1[0], selv),
                    __builtin_amdgcn_perm(a1[3], a1[2], selv)};
        bf16x8 af = *(bf16x8*)&au;
#pragma unroll
        for (int nt = 0; nt < 5; ++nt) {
            int browb = (nt * 8 + hp) * 32;
            u32x4 b0 = *(const u32x4*)(xt32 + browb + pa1);
            u32x4 b1 = *(const u32x4*)(xt32 + browb + pa2);
            u32x4 bu = {__builtin_amdgcn_perm(b0[1], b0[0], selv),
                        __builtin_amdgcn_perm(b0[3], b0[2], selv),
                        __builtin_amdgcn_perm(b1[1], b1[0], selv),
                        __builtin_amdgcn_perm(b1[3], b1[2], selv)};
            bf16x8 bf = *(bf16x8*)&bu;
            acc[nt] = __builtin_amdgcn_mfma_f32_16x16x32_bf16(af, bf, acc[nt], 0, 0, 0);
        }
    };

    auto writeout = [&](int i, f32x4* acc) {
        float rden[4];
#pragma unroll
        for (int reg = 0; reg < 4; ++reg) {
            float d = __shfl(acc[4][reg], (lane & 48) | 14, 64);
            rden[reg] = __builtin_amdgcn_rcpf(d);
        }
        size_t nb = (size_t)i * 80 + l15;
#pragma unroll
        for (int reg = 0; reg < 4; ++reg) {
            int head = quad * 4 + reg;
            if (head < 10) {
                u16* hpn = aggb16 + (size_t)head * (size_t)PL40 * 2 + nb;
#pragma unroll
                for (int nt = 0; nt < 5; ++nt) {
                    float v = acc[nt][reg] * rden[reg];
                    u16 b = f2bfbits(v);
                    if (nt == 4 && l15 >= 14) b = 0;   // feats 78,79 -> 0
                    hpn[nt * 16] = b;
                }
            }
        }
    };

    f32x4 acc0[5], acc1[5];
#pragma unroll
    for (int nt = 0; nt < 5; ++nt) { acc0[nt] = (f32x4){0.f,0.f,0.f,0.f}; acc1[nt] = (f32x4){0.f,0.f,0.f,0.f}; }

    if (d0 <= 32 && d1 <= 32) {
        // fast pipelined path (covers ~99.96% of pairs)
        int s0 = (int)src_arr[rs0 + slot];
        int s1 = (int)src_arr[rs1 + slot];
        G1 g0, g1;
        gatherrows(s0, d0, g0);
        stage(g0, dstv0);              // vmcnt waits only g0's loads
        gatherrows(s1, d1, g1);        // issue node1 gathers (s1 long since arrived)
        __builtin_amdgcn_wave_barrier();
        domfma(acc0);                  // LDS frags + MFMA, overlaps g1 flight
        writeout(i0, acc0);            // global stores + shfl, overlaps g1 flight
        __builtin_amdgcn_wave_barrier();
        stage(g1, dstv1);              // by now most of g1 latency is hidden
        __builtin_amdgcn_wave_barrier();
        domfma(acc1);
        writeout(i1, acc1);
    } else {
        // serial fallback, same helpers
        int rss[2] = {rs0, rs1}, dd[2] = {d0, d1}, ii[2] = {i0, i1};
#pragma unroll
        for (int n = 0; n < 2; ++n) {
            f32x4* acc = (n == 0) ? acc0 : acc1;
            const float* dv = (n == 0) ? dstv0 : dstv1;
            for (int base = 0; base < dd[n]; base += 32) {
                int cnt = min(dd[n] - base, 32);
                int s = (int)src_arr[rss[n] + base + slot];
                G1 g;
                gatherrows(s, cnt, g);
                stage(g, dv);
                __builtin_amdgcn_wave_barrier();
                domfma(acc);
                __builtin_amdgcn_wave_barrier();
            }
            writeout(ii[n], acc);
        }
    }
}

// ---------------- gemmf v5: 128-row blocks, B-LDS-reads amortized over 2 row-tiles ----------------
// (r17-verified, 55us. r18's B2-register hoist REVERTED: VGPR 104->144 crossed the
// 128-VGPR occupancy step, halving waves/SIMD -> 80us. r16's A-dbuf also null.
// This structure is the best-known: DS-read-issue bound at ~55us with occupancy
// pinned by LDS at 2 blocks/CU; both escape directions measured and refuted.)
__global__ __launch_bounds__(256) void gemmf_kernel(const uint32* __restrict__ aggb,
                                                    const uint32* __restrict__ w1p,
                                                    const uint32* __restrict__ w2p,
                                                    const float* __restrict__ b1,
                                                    const float* __restrict__ w2as,
                                                    const float* __restrict__ w2ad,
                                                    u16* __restrict__ h2,
                                                    float* __restrict__ as2,
                                                    float* __restrict__ ad2) {
    __shared__ uint32 As[5128];     // aggb[h] 128 rows (5120 dw + 8 pad)
    __shared__ uint32 Bs1[3208];    // w1p[h] (3200 dw + 8 pad)
    __shared__ uint32 Bs2[5128];    // w2p[h] (5120 dw + 8 pad)
    __shared__ uint32 C1s[2568];    // relu(gemm1) bf16 [64][80], reused per rt (+8 pad)
    int tid = threadIdx.x, lane = tid & 63, wv = tid >> 6;
    int row0 = blockIdx.x * 128;
    int l15 = lane & 15, quad = lane >> 4;
    const u16* Asu = (const u16*)As;
    const u16* B1u = (const u16*)Bs1;
    const u16* B2u = (const u16*)Bs2;
    const u16* C1u = (const u16*)C1s;
    u16* Cw = (u16*)C1s;

    f32x4 acc2[2][8];
#pragma unroll
    for (int rt = 0; rt < 2; ++rt)
#pragma unroll
        for (int nj = 0; nj < 8; ++nj) acc2[rt][nj] = (f32x4){0.f, 0.f, 0.f, 0.f};
    float s2p[2][4] = {}, d2p[2][4] = {};

    int abase64 = (wv * 16 + l15) * 80 + quad * 8;   // intra-rt row offset (A frag / C1 frag)
    int b1base[5];
#pragma unroll
    for (int nj = 0; nj < 5; ++nj) b1base[nj] = (nj * 16 + l15) * 80 + quad * 8;
    int b2base[8];
#pragma unroll
    for (int nj = 0; nj < 8; ++nj) b2base[nj] = (nj * 16 + l15) * 80 + quad * 8;
    bf16x8 z8 = {0, 0, 0, 0, 0, 0, 0, 0};
    int rl0 = wv * 16 + quad * 4;

    auto stageA = [&](int h) {
        const uint32* aplane = aggb + (size_t)h * PL40 + (size_t)row0 * 40;
        for (int t = wv; t < 20; t += 4)
            cp16(As + t * 256, aplane + t * 256, lane);
    };
    auto stageB = [&](int h) {
        const uint32* w1pl = w1p + (size_t)h * 3200;
        const uint32* w2pl = w2p + (size_t)h * 5120;
        // Bs1: 3200 dwords = 12 full tiles + one half-masked tile (lanes < 32)
        int tw0 = wv * 3, tw1 = (wv == 3) ? 12 : wv * 3 + 3;
        for (int t = tw0; t < tw1; ++t)
            cp16(Bs1 + t * 256, w1pl + t * 256, lane);
        if (wv == 3 && lane < 32)
            cp16(Bs1 + 12 * 256, w1pl + 12 * 256, lane);
#pragma unroll
        for (int t = 0; t < 5; ++t)
            cp16(Bs2 + (wv * 5 + t) * 256, w2pl + (wv * 5 + t) * 256, lane);
    };

    stageA(0);
    stageB(0);
    for (int h = 0; h < 10; ++h) {
        __syncthreads();               // staging for head h complete
#pragma unroll
        for (int rt = 0; rt < 2; ++rt) {
            int abase = rt * 64 * 80 + abase64;      // u16 offset into 128-row As
            // gemm1: C1 = aggb[h][rt*64..] @ w1p[h]
            f32x4 acc1[5];
#pragma unroll
            for (int nj = 0; nj < 5; ++nj) acc1[nj] = (f32x4){0.f, 0.f, 0.f, 0.f};
#pragma unroll
            for (int ks = 0; ks < 96; ks += 32) {
                bf16x8 a = *(const bf16x8*)(Asu + abase + ks);
                if (ks == 64 && quad >= 2) a = z8;
#pragma unroll
                for (int nj = 0; nj < 5; ++nj) {
                    bf16x8 b = *(const bf16x8*)(B1u + b1base[nj] + ks);
                    acc1[nj] = __builtin_amdgcn_mfma_f32_16x16x32_bf16(a, b, acc1[nj], 0, 0, 0);
                }
            }
            // epilogue: bias+relu -> C1s (wave-local rows), accumulate as2/ad2 partials
#pragma unroll
            for (int nj = 0; nj < 5; ++nj) {
                int col = nj * 16 + l15;
                if (col < 78) {
                    int gc = h * 78 + col;
                    float bia = b1[gc], was = w2as[gc], wad = w2ad[gc];
#pragma unroll
                    for (int reg = 0; reg < 4; ++reg) {
                        float v = fmaxf(acc1[nj][reg] + bia, 0.f);
                        Cw[(rl0 + reg) * 80 + col] = f2bfbits(v);
                        s2p[rt][reg] = fmaf(v, was, s2p[rt][reg]);
                        d2p[rt][reg] = fmaf(v, wad, d2p[rt][reg]);
                    }
                } else {
#pragma unroll
                    for (int reg = 0; reg < 4; ++reg) Cw[(rl0 + reg) * 80 + col] = 0;
                }
            }
            __builtin_amdgcn_wave_barrier();
            // gemm2 accumulate: acc2[rt] += relu(C1) @ w2p[h]
#pragma unroll
            for (int ks = 0; ks < 96; ks += 32) {
                bf16x8 a = *(const bf16x8*)(C1u + abase64 + ks);
                if (ks == 64 && quad >= 2) a = z8;
#pragma unroll
                for (int nj = 0; nj < 8; ++nj) {
                    bf16x8 b = *(const bf16x8*)(B2u + b2base[nj] + ks);
                    acc2[rt][nj] = __builtin_amdgcn_mfma_f32_16x16x32_bf16(a, b, acc2[rt][nj], 0, 0, 0);
                }
            }
            __builtin_amdgcn_wave_barrier();   // C1s reuse ordering (same wave)
        }
        __syncthreads();               // all waves done reading As/Bs1/Bs2
        if (h < 9) { stageA(h + 1); stageB(h + 1); }
    }

    // write h2 (bf16)
#pragma unroll
    for (int rt = 0; rt < 2; ++rt)
#pragma unroll
        for (int nj = 0; nj < 8; ++nj) {
            int col = nj * 16 + l15;
#pragma unroll
            for (int reg = 0; reg < 4; ++reg) {
                int r = row0 + rt * 64 + rl0 + reg;
                if (r < N_NODES) h2[(size_t)r * OUT2 + col] = f2bfbits(acc2[rt][nj][reg]);
            }
        }
    // as2/ad2: reduce over the 16 l15 lanes (cols), write once per rt
#pragma unroll
    for (int off = 1; off < 16; off <<= 1)
#pragma unroll
        for (int rt = 0; rt < 2; ++rt)
#pragma unroll
            for (int reg = 0; reg < 4; ++reg) {
                s2p[rt][reg] += __shfl_xor(s2p[rt][reg], off, 64);
                d2p[rt][reg] += __shfl_xor(d2p[rt][reg], off, 64);
            }
    if (l15 == 0) {
#pragma unroll
        for (int rt = 0; rt < 2; ++rt)
#pragma unroll
            for (int reg = 0; reg < 4; ++reg) {
                int r = row0 + rt * 64 + rl0 + reg;
                if (r < N_NODES) {
                    as2[r] = s2p[rt][reg];
                    ad2[r] = d2p[rt][reg];
                }
            }
    }
}

// ---------------- layer-2 aggregation + pool (fused expw2, 8-deep gather ILP, block max pre-reduce) ----------------
__global__ __launch_bounds__(256) void agg2_kernel(const int* __restrict__ row_ptr,
                                                   const u16* __restrict__ src_arr,
                                                   const float* __restrict__ as2,
                                                   const float* __restrict__ ad2,
                                                   const uint32* __restrict__ h2u,
                                                   const float* __restrict__ b2,
                                                   const int* __restrict__ batch,
                                                   float* __restrict__ pooled) {
    __shared__ float w_sh[4][64];
    __shared__ int src_sh[4][64];
    __shared__ float red[4][128];
    __shared__ int gsh[4];
    int tid = threadIdx.x, lane = tid & 63, wv = tid >> 6;
    int i = blockIdx.x * 4 + wv;
    int rs = row_ptr[i], deg = row_ptr[i + 1] - rs;
    float ad2i = ad2[i];   // wave-uniform dst projection (expw2 fused)

    f32x2 acc = {0.f, 0.f};
    float den = 0.f;
    if (deg <= 64) {
        if (lane < deg) {
            int s = (int)src_arr[rs + lane];
            float w = __expf(lrelu(as2[s] + ad2i));
            den = w;
            w_sh[wv][lane] = w;
            src_sh[wv][lane] = s;
        }
        __builtin_amdgcn_wave_barrier();
#pragma unroll
        for (int off = 1; off < 64; off <<= 1) den += __shfl_xor(den, off, 64);
        float rden = __builtin_amdgcn_rcpf(den);
        int cnt = deg, eix = 0;
        for (; eix + 7 < cnt; eix += 8) {
            int ss[8];
            float ww[8];
            uint32 uu[8];
#pragma unroll
            for (int q = 0; q < 8; ++q) {
                ss[q] = src_sh[wv][eix + q];
                ww[q] = w_sh[wv][eix + q];
            }
#pragma unroll
            for (int q = 0; q < 8; ++q) uu[q] = h2u[(size_t)ss[q] * 64 + lane];
#pragma unroll
            for (int q = 0; q < 8; ++q) acc = ww[q] * bf2(uu[q]) + acc;
        }
        for (; eix < cnt; ++eix) {
            int s0 = src_sh[wv][eix];
            float w0 = w_sh[wv][eix];
            uint32 u0 = h2u[(size_t)s0 * 64 + lane];
            acc = w0 * bf2(u0) + acc;
        }
        acc *= rden;
    } else {
        for (int eix = lane; eix < deg; eix += 64)
            den += __expf(lrelu(as2[(int)src_arr[rs + eix]] + ad2i));
#pragma unroll
        for (int off = 1; off < 64; off <<= 1) den += __shfl_xor(den, off, 64);
        float rden = __builtin_amdgcn_rcpf(den);
        for (int base = 0; base < deg; base += 64) {
            int cnt = min(deg - base, 64);
            if (lane < cnt) {
                int s = (int)src_arr[rs + base + lane];
                w_sh[wv][lane] = __expf(lrelu(as2[s] + ad2i));
                src_sh[wv][lane] = s;
            }
            __builtin_amdgcn_wave_barrier();
            int eix = 0;
            for (; eix + 7 < cnt; eix += 8) {
                int ss[8];
                float ww[8];
                uint32 uu[8];
#pragma unroll
                for (int q = 0; q < 8; ++q) {
                    ss[q] = src_sh[wv][eix + q];
                    ww[q] = w_sh[wv][eix + q];
                }
#pragma unroll
                for (int q = 0; q < 8; ++q) uu[q] = h2u[(size_t)ss[q] * 64 + lane];
#pragma unroll
                for (int q = 0; q < 8; ++q) acc = ww[q] * bf2(uu[q]) + acc;
            }
            for (; eix < cnt; ++eix) {
                int s0 = src_sh[wv][eix];
                float w0 = w_sh[wv][eix];
                uint32 u0 = h2u[(size_t)s0 * 64 + lane];
                acc = w0 * bf2(u0) + acc;
            }
            __builtin_amdgcn_wave_barrier();
        }
        acc *= rden;
    }
    float2 bv = ((const float2*)b2)[lane];
    float v0 = fmaxf(acc.x + bv.x, 0.f);
    float v1 = fmaxf(acc.y + bv.y, 0.f);
    int g = batch[i];
    // block-level max pre-reduction: batch is sorted, so the block's 4 nodes usually
    // share one graph -> ~4x fewer device-scope atomics.
    red[wv][2 * lane] = v0;
    red[wv][2 * lane + 1] = v1;
    if (lane == 0) gsh[wv] = g;
    __syncthreads();
    bool leader = true;
#pragma unroll
    for (int w2i = 0; w2i < 3; ++w2i)
        if (w2i < wv && gsh[w2i] == g) leader = false;
    if (leader) {
        float m0 = v0, m1 = v1;
#pragma unroll
        for (int w2i = 1; w2i < 4; ++w2i) {
            if (w2i > wv && gsh[w2i] == g) {
                m0 = fmaxf(m0, red[w2i][2 * lane]);
                m1 = fmaxf(m1, red[w2i][2 * lane + 1]);
            }
        }
        atomicMax((int*)&pooled[g * OUT2 + 2 * lane], __float_as_int(m0));
        atomicMax((int*)&pooled[g * OUT2 + 2 * lane + 1], __float_as_int(m1));
    }
}

// ---------------- final FC + relu ----------------
__global__ __launch_bounds__(128) void fc_kernel(const float* __restrict__ pooled,
                                                 const float* __restrict__ fcW,
                                                 const float* __restrict__ fcb,
                                                 float* __restrict__ out) {
    int g = blockIdx.x, tid = threadIdx.x;
    __shared__ float p[128];
    p[tid] = pooled[g * OUT2 + tid];
    __syncthreads();
    float acc = fcb[tid];
    for (int k = 0; k < 128; ++k) acc = fmaf(p[k], fcW[k * OUT2 + tid], acc);
    out[g * OUT2 + tid] = fmaxf(acc, 0.f);
}

extern "C" void kernel_launch(void* const* d_in, const int* in_sizes, int n_in,
                              void* d_out, int out_size, void* d_ws, size_t ws_size,
                              hipStream_t stream) {
    const float* x      = (const float*)d_in[0];
    const int*   ei     = (const int*)d_in[1];
    const int*   batch  = (const int*)d_in[2];
    const float* W1     = (const float*)d_in[4];
    const float* a_src1 = (const float*)d_in[5];
    const float* a_dst1 = (const float*)d_in[6];
    const float* b1     = (const float*)d_in[7];
    const float* W2     = (const float*)d_in[8];
    const float* a_src2 = (const float*)d_in[9];
    const float* a_dst2 = (const float*)d_in[10];
    const float* b2     = (const float*)d_in[11];
    const float* fcW    = (const float*)d_in[12];
    const float* fcb    = (const float*)d_in[13];
    float* out = (float*)d_out;

    size_t off = 0;
    char* base = (char*)d_ws;
    auto alloc = [&](size_t bytes) -> void* {
        void* p = base + off;
        off += (bytes + 255) & ~(size_t)255;
        return p;
    };
    uint32* aggb  = (uint32*)alloc(PL40 * 10 * 4);            // [10][NP][40u]
    u16* h2arena  = (u16*)alloc((size_t)N_NODES * OUT2 * 2);  // h2; xbp aliases early
    u16* h2   = h2arena;
    u16* xbp  = h2arena;                                      // [NP][80 u16] = 8.0 MB < 12.8 MB ✓
    float* asd1 = (float*)alloc((size_t)N_NODES * 20 * 4);
    float* asrc = (float*)alloc((size_t)N_NODES * 12 * 4);    // compact src projections
    float* as2  = (float*)alloc((size_t)N_NODES * 4);
    float* ad2  = (float*)alloc((size_t)N_NODES * 4);
    u16* w1p    = (u16*)alloc((size_t)(10 * 80 * 80) * 2 + 1024);  // + stage slack
    u16* w2p    = (u16*)alloc((size_t)(10 * 128 * 80) * 2);
    u16* VAT    = (u16*)alloc((size_t)32 * 80 * 2);
    float* w2as = (float*)alloc((size_t)D1 * 4);
    float* w2ad = (float*)alloc((size_t)D1 * 4);
    float* pooled = (float*)alloc((size_t)NGRAPH * OUT2 * 4);
    int* deg     = (int*)alloc((size_t)N_NODES * 4);
    int* row_ptr = (int*)alloc((size_t)(N_NODES + 1) * 4);
    int* rank    = (int*)alloc((size_t)ETOT * 4);
    u16* src_arr = (u16*)alloc((size_t)ETOT * 2);
    int* bsum    = (int*)alloc(196 * 4);
    int* boff    = (int*)alloc(196 * 4);

    hipMemsetAsync(deg, 0, (size_t)N_NODES * 4, stream);
    hipMemsetAsync(pooled, 0, (size_t)NGRAPH * OUT2 * 4, stream);

    prep_kernel<<<2048, 256, 0, stream>>>(x, W1, W2, xbp, w1p, w2p);
    prep2_kernel<<<8, 256, 0, stream>>>(W1, a_src1, a_dst1, W2, a_src2, a_dst2,
                                        VAT, w2as, w2ad);
    alphas1x_kernel<<<391, 256, 0, stream>>>((const uint32*)xbp, (const uint32*)VAT,
                                             asd1, asrc);
    histrank_kernel<<<(ETOT + 255) / 256, 256, 0, stream>>>(ei, deg, rank);
    scan1_kernel<<<196, 256, 0, stream>>>(deg, row_ptr, bsum);
    scan2_kernel<<<1, 256, 0, stream>>>(bsum, boff);
    scan3_kernel<<<196, 256, 0, stream>>>(row_ptr, boff);
    scatter_kernel<<<(ETOT + 255) / 256, 256, 0, stream>>>(ei, row_ptr, rank, src_arr);
    agg1m_kernel<<<N_NODES / 4, 128, 0, stream>>>(row_ptr, src_arr, asrc, asd1,
                                                  (const uint32*)xbp, (u16*)aggb);
    gemmf_kernel<<<NP / 128, 256, 0, stream>>>(aggb, (const uint32*)w1p, (const uint32*)w2p,
                                               b1, w2as, w2ad, h2, as2, ad2);
    agg2_kernel<<<N_NODES / 4, 256, 0, stream>>>(row_ptr, src_arr, as2, ad2,
                                                 (const uint32*)h2, b2, batch, pooled);
    fc_kernel<<<NGRAPH, 128, 0, stream>>>(pooled, fcW, fcb, out);
}

// Round 20
// 300.038 us; speedup vs baseline: 1.1135x; 1.0247x over previous
//
#include <hip/hip_runtime.h>
#include <hip/hip_bf16.h>
#include <stdint.h>

typedef unsigned int uint32;
typedef unsigned short u16;
typedef __attribute__((ext_vector_type(8))) short bf16x8;
typedef __attribute__((ext_vector_type(4))) float f32x4;
typedef __attribute__((ext_vector_type(2))) float f32x2;
typedef uint32 u32x4 __attribute__((ext_vector_type(4)));

#define N_NODES 50000
#define NP      50048                 // padded row count (391*128)
#define N_EDGES 800000
#define ETOT    (N_EDGES + N_NODES)
#define F_INN   78
#define H1      10
#define D1      780
#define OUT2    128
#define NGRAPH  512
#define NEG_SLOPE 0.2f
#define PL40    ((size_t)NP * 40)     // uints per padded head-plane

#define HIST_BLKS  ((ETOT + 255) / 256)   // 3321
#define PREP_BLKS  2048
#define PREP2_BLKS 8
#define ALPHA_BLKS 391

__device__ __forceinline__ float lrelu(float v) { return v > 0.f ? v : NEG_SLOPE * v; }
__device__ __forceinline__ u16 f2bfbits(float f) {
    return __bfloat16_as_ushort(__float2bfloat16(f));
}
__device__ __forceinline__ uint32 packbf(float lo, float hi) {
    return (uint32)f2bfbits(lo) | ((uint32)f2bfbits(hi) << 16);
}
__device__ __forceinline__ f32x2 bf2(uint32 u) {
    __hip_bfloat162 b = *reinterpret_cast<__hip_bfloat162*>(&u);
    float2 t = __bfloat1622float2(b);
    return (f32x2){t.x, t.y};
}
__device__ __forceinline__ int esrc(const int* ei, int e) { return e < N_EDGES ? ei[e] : e - N_EDGES; }
__device__ __forceinline__ int edst(const int* ei, int e) { return e < N_EDGES ? ei[N_EDGES + e] : e - N_EDGES; }

// async global->LDS 16B per lane: lane i moves g[lane*16B] -> lds_base + lane*16B
typedef __attribute__((address_space(1))) const uint32 guint;
typedef __attribute__((address_space(3))) uint32 luint;
__device__ __forceinline__ void cp16(uint32* lds, const uint32* g, int lane) {
    __builtin_amdgcn_global_load_lds((guint*)(g + lane * 4), (luint*)lds, 16, 0, 0);
}

// ---------------- prephist: histrank ∪ prep ∪ prep2 (independent chains co-resident) ----------------
// hist blocks (latency-bound random atomics) issue first; prep's streaming bf16 convert
// fills their idle issue slots on the same CUs. Zero math changes vs the split kernels.
// xbp feat 78 = bf16(1.0) (agg1m free denominator); w1p rows 78/79 = 0; VAT col 78 = 0.
#define NXP (N_NODES * 80)
__global__ __launch_bounds__(256) void prephist_kernel(const float* __restrict__ x,
                                                       const float* __restrict__ W1,
                                                       const float* __restrict__ W2,
                                                       u16* __restrict__ xbp,
                                                       u16* __restrict__ w1p,
                                                       u16* __restrict__ w2p,
                                                       const int* __restrict__ ei,
                                                       int* __restrict__ deg,
                                                       int* __restrict__ rank,
                                                       const float* __restrict__ a_src1,
                                                       const float* __restrict__ a_dst1,
                                                       const float* __restrict__ a_src2,
                                                       const float* __restrict__ a_dst2,
                                                       u16* __restrict__ VAT,
                                                       float* __restrict__ w2as,
                                                       float* __restrict__ w2ad) {
    int b = blockIdx.x, tid = threadIdx.x;
    if (b < HIST_BLKS) {
        // histrank: degree histogram + per-edge rank
        int e = b * 256 + tid;
        if (e < ETOT) rank[e] = atomicAdd(&deg[edst(ei, e)], 1);
    } else if (b < HIST_BLKS + PREP_BLKS) {
        // prep: xbp [NP][80], w1p [10][80][80], w2p [10][128][80]
        int pb = b - HIST_BLKS;
        const int total = NXP + 10 * 80 * 80 + 10 * 128 * 80;
        for (int id = pb * 256 + tid; id < total; id += PREP_BLKS * 256) {
            if (id < NXP) {
                int n = id / 80, k = id - n * 80;
                xbp[id] = (k < 78) ? f2bfbits(x[n * 78 + k]) : ((k == 78) ? (u16)0x3F80 : (u16)0);
            } else if (id < NXP + 64000) {
                int t = id - NXP;
                int h = t / 6400, r = t - h * 6400;
                int n = r / 80, k = r - n * 80;
                w1p[t] = (n < 78 && k < 78) ? f2bfbits(W1[k * D1 + h * 78 + n]) : (u16)0;
            } else {
                int t = id - NXP - 64000;
                int h = t / 10240, r = t - h * 10240;
                int n = r / 80, k = r - n * 80;
                w2p[t] = (k < 78) ? f2bfbits(W2[(h * 78 + k) * OUT2 + n]) : (u16)0;
            }
        }
    } else {
        // prep2: VAT [32][80] + w2as/w2ad
        int pb = b - HIST_BLKS - PREP_BLKS;
        int gid = pb * 256 + tid;
        int gs = PREP2_BLKS * 256;
        for (int idx = gid; idx < 32 * 80; idx += gs) {
            int j = idx / 80, k = idx - j * 80;
            float s = 0.f;
            if (j < 20 && k < 78) {
                int h = (j < 10) ? j : j - 10;
                const float* vec = ((j < 10) ? a_src1 : a_dst1) + h * F_INN;
                const float* wrow = W1 + k * D1 + h * F_INN;
                for (int f = 0; f < F_INN; ++f) s = fmaf(wrow[f], vec[f], s);
                VAT[idx] = f2bfbits(s);
            } else {
                VAT[idx] = 0;
            }
        }
        for (int c = gid; c < D1; c += gs) {
            const float* r0 = W2 + (size_t)c * OUT2;
            float s = 0.f, d = 0.f;
            for (int j = 0; j < OUT2; ++j) {
                s = fmaf(r0[j], a_src2[j], s);
                d = fmaf(r0[j], a_dst2[j], d);
            }
            w2as[c] = s;
            w2ad[c] = d;
        }
    }
}

__global__ __launch_bounds__(256) void scan1_kernel(const int* __restrict__ deg,
                                                    int* __restrict__ row_ptr,
                                                    int* __restrict__ bsum) {
    __shared__ int buf[256];
    int tid = threadIdx.x;
    int i = blockIdx.x * 256 + tid;
    int v = (i < N_NODES) ? deg[i] : 0;
    buf[tid] = v;
    __syncthreads();
    for (int off = 1; off < 256; off <<= 1) {
        int t = (tid >= off) ? buf[tid - off] : 0;
        __syncthreads();
        buf[tid] += t;
        __syncthreads();
    }
    if (i < N_NODES) row_ptr[i] = buf[tid] - v;
    if (tid == 255) bsum[blockIdx.x] = buf[255];
}

__global__ __launch_bounds__(256) void scan2_kernel(const int* __restrict__ bsum,
                                                    int* __restrict__ boff) {
    __shared__ int buf[256];
    int tid = threadIdx.x;
    int v = (tid < 196) ? bsum[tid] : 0;
    buf[tid] = v;
    __syncthreads();
    for (int off = 1; off < 256; off <<= 1) {
        int t = (tid >= off) ? buf[tid - off] : 0;
        __syncthreads();
        buf[tid] += t;
        __syncthreads();
    }
    if (tid < 196) boff[tid] = buf[tid] - v;
}

__global__ __launch_bounds__(256) void scan3_kernel(int* __restrict__ row_ptr,
                                                    const int* __restrict__ boff) {
    int i = blockIdx.x * 256 + threadIdx.x;
    if (i < N_NODES) row_ptr[i] = row_ptr[i] + boff[blockIdx.x];
    if (i == 0) row_ptr[N_NODES] = ETOT;
}

// ---------------- alsc: scatter ∪ alphas1x (both ready after scan3+prephist) ----------------
// scatter's latency-bound random 2B stores overlap alphas1x's MFMA blocks on the same CUs.
// scatter blocks first (early issue); whole-block-uniform early return, so no divergent
// __syncthreads hazard. Math identical to the split kernels.
__global__ __launch_bounds__(256) void alsc_kernel(const uint32* __restrict__ xbu,
                                                   const uint32* __restrict__ vatu,
                                                   float* __restrict__ asd1,
                                                   float* __restrict__ asrc,
                                                   const int* __restrict__ ei,
                                                   const int* __restrict__ row_ptr,
                                                   const int* __restrict__ rank,
                                                   u16* __restrict__ src_arr) {
    __shared__ uint32 As[5136];
    __shared__ uint32 Bs[1296];
    int b = blockIdx.x;
    if (b < HIST_BLKS) {
        // atomic-free scatter: pos = row_ptr[dst] + rank[e]
        int e = b * 256 + threadIdx.x;
        if (e < ETOT) {
            int d = edst(ei, e);
            src_arr[row_ptr[d] + rank[e]] = (u16)esrc(ei, e);
        }
        return;
    }
    // alphas1x: xbp[128 rows] @ VAT^T -> asd1[N][20] + compact asrc[N][12]
    int tid = threadIdx.x, lane = tid & 63, wv = tid >> 6;
    int row0 = (b - HIST_BLKS) * 128;
    const uint32* aplane = xbu + (size_t)row0 * 40;

#pragma unroll
    for (int t = 0; t < 5; ++t)
        cp16(As + wv * 1280 + t * 256, aplane + wv * 1280 + t * 256, lane);
    if (wv == 0) {
#pragma unroll
        for (int t = 0; t < 5; ++t)
            cp16(Bs + t * 256, vatu + t * 256, lane);
    }
    __syncthreads();

    int l15 = lane & 15, quad = lane >> 4;
    const u16* Asu = (const u16*)As;
    const u16* Bsu = (const u16*)Bs;
    f32x4 acc[2][2];
#pragma unroll
    for (int mi = 0; mi < 2; ++mi)
#pragma unroll
        for (int nj = 0; nj < 2; ++nj) acc[mi][nj] = (f32x4){0.f, 0.f, 0.f, 0.f};

    int abase[2], bbase[2];
#pragma unroll
    for (int mi = 0; mi < 2; ++mi) abase[mi] = (wv * 32 + mi * 16 + l15) * 80 + quad * 8;
#pragma unroll
    for (int nj = 0; nj < 2; ++nj) bbase[nj] = (nj * 16 + l15) * 80 + quad * 8;

    bf16x8 z8 = {0, 0, 0, 0, 0, 0, 0, 0};
#pragma unroll
    for (int ks = 0; ks < 96; ks += 32) {
        bf16x8 a[2], b2[2];
#pragma unroll
        for (int mi = 0; mi < 2; ++mi) {
            a[mi] = *(const bf16x8*)(Asu + abase[mi] + ks);
            if (ks == 64 && quad >= 2) a[mi] = z8;
        }
#pragma unroll
        for (int nj = 0; nj < 2; ++nj) b2[nj] = *(const bf16x8*)(Bsu + bbase[nj] + ks);
#pragma unroll
        for (int mi = 0; mi < 2; ++mi)
#pragma unroll
            for (int nj = 0; nj < 2; ++nj)
                acc[mi][nj] = __builtin_amdgcn_mfma_f32_16x16x32_bf16(a[mi], b2[nj], acc[mi][nj], 0, 0, 0);
    }

#pragma unroll
    for (int mi = 0; mi < 2; ++mi)
#pragma unroll
        for (int nj = 0; nj < 2; ++nj) {
            int col = nj * 16 + l15;
            if (col < 20) {
#pragma unroll
                for (int reg = 0; reg < 4; ++reg) {
                    int row = row0 + wv * 32 + mi * 16 + quad * 4 + reg;
                    if (row < N_NODES) {
                        asd1[(size_t)row * 20 + col] = acc[mi][nj][reg];
                        if (col < 10) asrc[(size_t)row * 12 + col] = acc[mi][nj][reg];
                    }
                }
            }
        }
}

// gathered per-edge registers for agg1m (one LDS slot's worth).
// Attention floats UNIONED across half-waves (r13: kept VGPR <= 64).
// half0: af = heads 0-3, af2 = heads 4-5.  half1: af = heads 6-9, af2 unused.
struct G1 {
    float4 af;
    float2 af2;
    u32x4 xv[5];             // x row (40 uints, this half's 20)
    int valid;
};

// ---------------- agg1m v5: 2-node pipeline, 2-wave blocks (r13, verified) ----------------
__global__ __launch_bounds__(128) void agg1m_kernel(const int* __restrict__ row_ptr,
                                                    const u16* __restrict__ src_arr,
                                                    const float* __restrict__ asrc,
                                                    const float* __restrict__ asd1,
                                                    const uint32* __restrict__ xbu,
                                                    u16* __restrict__ aggb16) {
    __shared__ uint32 S[2][1536];
    int tid = threadIdx.x, lane = tid & 63, wv = tid >> 6;
    int ip = blockIdx.x * 2 + wv;            // pair index
    int i0 = ip * 2, i1 = i0 + 1;
    int rs0 = row_ptr[i0], d0 = row_ptr[i0 + 1] - rs0;
    int rs1 = row_ptr[i1], d1 = row_ptr[i1 + 1] - rs1;
    uint32* xt32 = S[wv];            // [40 fp][32 slots] rotated
    uint32* wm32 = xt32 + 1280;      // [8 hp][32 slots] rotated
    int l15 = lane & 15, quad = lane >> 4;
    int slot = lane & 31, half = lane >> 5;
    u32x4 z4 = {0, 0, 0, 0};
    // head rows 10..15 (hp 5..7) stay zero forever
    if (lane < 24) *(u32x4*)(wm32 + 160 + lane * 4) = z4;
    uint32 selv = (l15 & 1) ? 0x07060302u : 0x05040100u;
    int hp = l15 >> 1;
    int pa1 = (quad * 8 + 4 * hp) & 31;
    int pa2 = (pa1 + 4) & 31;

    float dstv0[10], dstv1[10];
#pragma unroll
    for (int q = 0; q < 10; ++q) dstv0[q] = asd1[(size_t)i0 * 20 + 10 + q];
#pragma unroll
    for (int q = 0; q < 10; ++q) dstv1[q] = asd1[(size_t)i1 * 20 + 10 + q];

    auto gatherrows = [&](int s, int cnt, G1& g) {
        g.valid = slot < cnt;
        int srow = g.valid ? s : 0;
        const float* arow = asrc + (size_t)srow * 12;
        if (half == 0) {
            if (g.valid) { g.af = *(const float4*)(arow); g.af2 = *(const float2*)(arow + 4); }
        } else {
            if (g.valid) {
                float2 t0 = *(const float2*)(arow + 6);
                float2 t1 = *(const float2*)(arow + 8);
                g.af = make_float4(t0.x, t0.y, t1.x, t1.y);
            }
        }
#pragma unroll
        for (int t = 0; t < 5; ++t) {
            int c4 = 2 * t + half;
            g.xv[t] = z4;
            if (g.valid) g.xv[t] = *(const u32x4*)(xbu + (size_t)srow * 40 + c4 * 4);
        }
    };

    auto stage = [&](const G1& g, const float* dstv) {
        if (half == 0) {
            uint32 u0 = 0, u1 = 0, u2 = 0;
            if (g.valid) {
                u0 = packbf(__expf(lrelu(g.af.x + dstv[0])), __expf(lrelu(g.af.y + dstv[1])));
                u1 = packbf(__expf(lrelu(g.af.z + dstv[2])), __expf(lrelu(g.af.w + dstv[3])));
                u2 = packbf(__expf(lrelu(g.af2.x + dstv[4])), __expf(lrelu(g.af2.y + dstv[5])));
            }
            wm32[0 * 32 + (slot & 31)] = u0;
            wm32[1 * 32 + ((slot + 4) & 31)] = u1;
            wm32[2 * 32 + ((slot + 8) & 31)] = u2;
        } else {
            uint32 u3 = 0, u4 = 0;
            if (g.valid) {
                u3 = packbf(__expf(lrelu(g.af.x + dstv[6])), __expf(lrelu(g.af.y + dstv[7])));
                u4 = packbf(__expf(lrelu(g.af.z + dstv[8])), __expf(lrelu(g.af.w + dstv[9])));
            }
            wm32[3 * 32 + ((slot + 12) & 31)] = u3;
            wm32[4 * 32 + ((slot + 16) & 31)] = u4;
        }
#pragma unroll
        for (int t = 0; t < 5; ++t) {
            int c4 = 2 * t + half;
            uint32* rowp = xt32 + (4 * c4) * 32;
#pragma unroll
            for (int k = 0; k < 4; ++k)
                rowp[k * 32 + ((slot + 16 * c4 + 4 * k) & 31)] = g.xv[t][k];
        }
    };

    auto domfma = [&](f32x4* acc) {
        int arow2 = hp * 32;
        u32x4 a0 = *(const u32x4*)(wm32 + arow2 + pa1);
        u32x4 a1 = *(const u32x4*)(wm32 + arow2 + pa2);
        u32x4 au = {__builtin_amdgcn_perm(a0[1], a0[0], selv),
                    __builtin_amdgcn_perm(a0[3], a0[2], selv),
                    __builtin_amdgcn_perm(a1[1], a1[0], selv),
                    __builtin_amdgcn_perm(a1[3], a1[2], selv)};
        bf16x8 af = *(bf16x8*)&au;
#pragma unroll
        for (int nt = 0; nt < 5; ++nt) {
            int browb = (nt * 8 + hp) * 32;
            u32x4 b0 = *(const u32x4*)(xt32 + browb + pa1);
            u32x4 b1 = *(const u32x4*)(xt32 + browb + pa2);
            u32x4 bu = {__builtin_amdgcn_perm(b0[1], b0[0], selv),
                        __builtin_amdgcn_perm(b0[3], b0[2], selv),
                        __builtin_amdgcn_perm(b1[1], b1[0], selv),
                        __builtin_amdgcn_perm(b1[3], b1[2], selv)};
            bf16x8 bf = *(bf16x8*)&bu;
            acc[nt] = __builtin_amdgcn_mfma_f32_16x16x32_bf16(af, bf, acc[nt], 0, 0, 0);
        }
    };

    auto writeout = [&](int i, f32x4* acc) {
        float rden[4];
#pragma unroll
        for (int reg = 0; reg < 4; ++reg) {
            float d = __shfl(acc[4][reg], (lane & 48) | 14, 64);
            rden[reg] = __builtin_amdgcn_rcpf(d);
        }
        size_t nb = (size_t)i * 80 + l15;
#pragma unroll
        for (int reg = 0; reg < 4; ++reg) {
            int head = quad * 4 + reg;
            if (head < 10) {
                u16* hpn = aggb16 + (size_t)head * (size_t)PL40 * 2 + nb;
#pragma unroll
                for (int nt = 0; nt < 5; ++nt) {
                    float v = acc[nt][reg] * rden[reg];
                    u16 b = f2bfbits(v);
                    if (nt == 4 && l15 >= 14) b = 0;   // feats 78,79 -> 0
                    hpn[nt * 16] = b;
                }
            }
        }
    };

    f32x4 acc0[5], acc1[5];
#pragma unroll
    for (int nt = 0; nt < 5; ++nt) { acc0[nt] = (f32x4){0.f,0.f,0.f,0.f}; acc1[nt] = (f32x4){0.f,0.f,0.f,0.f}; }

    if (d0 <= 32 && d1 <= 32) {
        // fast pipelined path (covers ~99.96% of pairs)
        int s0 = (int)src_arr[rs0 + slot];
        int s1 = (int)src_arr[rs1 + slot];
        G1 g0, g1;
        gatherrows(s0, d0, g0);
        stage(g0, dstv0);              // vmcnt waits only g0's loads
        gatherrows(s1, d1, g1);        // issue node1 gathers (s1 long since arrived)
        __builtin_amdgcn_wave_barrier();
        domfma(acc0);                  // LDS frags + MFMA, overlaps g1 flight
        writeout(i0, acc0);            // global stores + shfl, overlaps g1 flight
        __builtin_amdgcn_wave_barrier();
        stage(g1, dstv1);              // by now most of g1 latency is hidden
        __builtin_amdgcn_wave_barrier();
        domfma(acc1);
        writeout(i1, acc1);
    } else {
        // serial fallback, same helpers
        int rss[2] = {rs0, rs1}, dd[2] = {d0, d1}, ii[2] = {i0, i1};
#pragma unroll
        for (int n = 0; n < 2; ++n) {
            f32x4* acc = (n == 0) ? acc0 : acc1;
            const float* dv = (n == 0) ? dstv0 : dstv1;
            for (int base = 0; base < dd[n]; base += 32) {
                int cnt = min(dd[n] - base, 32);
                int s = (int)src_arr[rss[n] + base + slot];
                G1 g;
                gatherrows(s, cnt, g);
                stage(g, dv);
                __builtin_amdgcn_wave_barrier();
                domfma(acc);
                __builtin_amdgcn_wave_barrier();
            }
            writeout(ii[n], acc);
        }
    }
}

// ---------------- gemmf v5: 128-row blocks, B-LDS-reads amortized over 2 row-tiles ----------------
// (r17/r19-verified, 55us. All escape directions measured and refuted: direct-global B
// +50us, B2-register hoist +25us via 128-VGPR cliff, A-dbuf null. Best-known structure.)
__global__ __launch_bounds__(256) void gemmf_kernel(const uint32* __restrict__ aggb,
                                                    const uint32* __restrict__ w1p,
                                                    const uint32* __restrict__ w2p,
                                                    const float* __restrict__ b1,
                                                    const float* __restrict__ w2as,
                                                    const float* __restrict__ w2ad,
                                                    u16* __restrict__ h2,
                                                    float* __restrict__ as2,
                                                    float* __restrict__ ad2) {
    __shared__ uint32 As[5128];     // aggb[h] 128 rows (5120 dw + 8 pad)
    __shared__ uint32 Bs1[3208];    // w1p[h] (3200 dw + 8 pad)
    __shared__ uint32 Bs2[5128];    // w2p[h] (5120 dw + 8 pad)
    __shared__ uint32 C1s[2568];    // relu(gemm1) bf16 [64][80], reused per rt (+8 pad)
    int tid = threadIdx.x, lane = tid & 63, wv = tid >> 6;
    int row0 = blockIdx.x * 128;
    int l15 = lane & 15, quad = lane >> 4;
    const u16* Asu = (const u16*)As;
    const u16* B1u = (const u16*)Bs1;
    const u16* B2u = (const u16*)Bs2;
    const u16* C1u = (const u16*)C1s;
    u16* Cw = (u16*)C1s;

    f32x4 acc2[2][8];
#pragma unroll
    for (int rt = 0; rt < 2; ++rt)
#pragma unroll
        for (int nj = 0; nj < 8; ++nj) acc2[rt][nj] = (f32x4){0.f, 0.f, 0.f, 0.f};
    float s2p[2][4] = {}, d2p[2][4] = {};

    int abase64 = (wv * 16 + l15) * 80 + quad * 8;   // intra-rt row offset (A frag / C1 frag)
    int b1base[5];
#pragma unroll
    for (int nj = 0; nj < 5; ++nj) b1base[nj] = (nj * 16 + l15) * 80 + quad * 8;
    int b2base[8];
#pragma unroll
    for (int nj = 0; nj < 8; ++nj) b2base[nj] = (nj * 16 + l15) * 80 + quad * 8;
    bf16x8 z8 = {0, 0, 0, 0, 0, 0, 0, 0};
    int rl0 = wv * 16 + quad * 4;

    auto stageA = [&](int h) {
        const uint32* aplane = aggb + (size_t)h * PL40 + (size_t)row0 * 40;
        for (int t = wv; t < 20; t += 4)
            cp16(As + t * 256, aplane + t * 256, lane);
    };
    auto stageB = [&](int h) {
        const uint32* w1pl = w1p + (size_t)h * 3200;
        const uint32* w2pl = w2p + (size_t)h * 5120;
        // Bs1: 3200 dwords = 12 full tiles + one half-masked tile (lanes < 32)
        int tw0 = wv * 3, tw1 = (wv == 3) ? 12 : wv * 3 + 3;
        for (int t = tw0; t < tw1; ++t)
            cp16(Bs1 + t * 256, w1pl + t * 256, lane);
        if (wv == 3 && lane < 32)
            cp16(Bs1 + 12 * 256, w1pl + 12 * 256, lane);
#pragma unroll
        for (int t = 0; t < 5; ++t)
            cp16(Bs2 + (wv * 5 + t) * 256, w2pl + (wv * 5 + t) * 256, lane);
    };

    stageA(0);
    stageB(0);
    for (int h = 0; h < 10; ++h) {
        __syncthreads();               // staging for head h complete
#pragma unroll
        for (int rt = 0; rt < 2; ++rt) {
            int abase = rt * 64 * 80 + abase64;      // u16 offset into 128-row As
            // gemm1: C1 = aggb[h][rt*64..] @ w1p[h]
            f32x4 acc1[5];
#pragma unroll
            for (int nj = 0; nj < 5; ++nj) acc1[nj] = (f32x4){0.f, 0.f, 0.f, 0.f};
#pragma unroll
            for (int ks = 0; ks < 96; ks += 32) {
                bf16x8 a = *(const bf16x8*)(Asu + abase + ks);
                if (ks == 64 && quad >= 2) a = z8;
#pragma unroll
                for (int nj = 0; nj < 5; ++nj) {
                    bf16x8 b = *(const bf16x8*)(B1u + b1base[nj] + ks);
                    acc1[nj] = __builtin_amdgcn_mfma_f32_16x16x32_bf16(a, b, acc1[nj], 0, 0, 0);
                }
            }
            // epilogue: bias+relu -> C1s (wave-local rows), accumulate as2/ad2 partials
#pragma unroll
            for (int nj = 0; nj < 5; ++nj) {
                int col = nj * 16 + l15;
                if (col < 78) {
                    int gc = h * 78 + col;
                    float bia = b1[gc], was = w2as[gc], wad = w2ad[gc];
#pragma unroll
                    for (int reg = 0; reg < 4; ++reg) {
                        float v = fmaxf(acc1[nj][reg] + bia, 0.f);
                        Cw[(rl0 + reg) * 80 + col] = f2bfbits(v);
                        s2p[rt][reg] = fmaf(v, was, s2p[rt][reg]);
                        d2p[rt][reg] = fmaf(v, wad, d2p[rt][reg]);
                    }
                } else {
#pragma unroll
                    for (int reg = 0; reg < 4; ++reg) Cw[(rl0 + reg) * 80 + col] = 0;
                }
            }
            __builtin_amdgcn_wave_barrier();
            // gemm2 accumulate: acc2[rt] += relu(C1) @ w2p[h]
#pragma unroll
            for (int ks = 0; ks < 96; ks += 32) {
                bf16x8 a = *(const bf16x8*)(C1u + abase64 + ks);
                if (ks == 64 && quad >= 2) a = z8;
#pragma unroll
                for (int nj = 0; nj < 8; ++nj) {
                    bf16x8 b = *(const bf16x8*)(B2u + b2base[nj] + ks);
                    acc2[rt][nj] = __builtin_amdgcn_mfma_f32_16x16x32_bf16(a, b, acc2[rt][nj], 0, 0, 0);
                }
            }
            __builtin_amdgcn_wave_barrier();   // C1s reuse ordering (same wave)
        }
        __syncthreads();               // all waves done reading As/Bs1/Bs2
        if (h < 9) { stageA(h + 1); stageB(h + 1); }
    }

    // write h2 (bf16)
#pragma unroll
    for (int rt = 0; rt < 2; ++rt)
#pragma unroll
        for (int nj = 0; nj < 8; ++nj) {
            int col = nj * 16 + l15;
#pragma unroll
            for (int reg = 0; reg < 4; ++reg) {
                int r = row0 + rt * 64 + rl0 + reg;
                if (r < N_NODES) h2[(size_t)r * OUT2 + col] = f2bfbits(acc2[rt][nj][reg]);
            }
        }
    // as2/ad2: reduce over the 16 l15 lanes (cols), write once per rt
#pragma unroll
    for (int off = 1; off < 16; off <<= 1)
#pragma unroll
        for (int rt = 0; rt < 2; ++rt)
#pragma unroll
            for (int reg = 0; reg < 4; ++reg) {
                s2p[rt][reg] += __shfl_xor(s2p[rt][reg], off, 64);
                d2p[rt][reg] += __shfl_xor(d2p[rt][reg], off, 64);
            }
    if (l15 == 0) {
#pragma unroll
        for (int rt = 0; rt < 2; ++rt)
#pragma unroll
            for (int reg = 0; reg < 4; ++reg) {
                int r = row0 + rt * 64 + rl0 + reg;
                if (r < N_NODES) {
                    as2[r] = s2p[rt][reg];
                    ad2[r] = d2p[rt][reg];
                }
            }
    }
}

// ---------------- layer-2 aggregation + pool (fused expw2, 8-deep gather ILP, block max pre-reduce) ----------------
__global__ __launch_bounds__(256) void agg2_kernel(const int* __restrict__ row_ptr,
                                                   const u16* __restrict__ src_arr,
                                                   const float* __restrict__ as2,
                                                   const float* __restrict__ ad2,
                                                   const uint32* __restrict__ h2u,
                                                   const float* __restrict__ b2,
                                                   const int* __restrict__ batch,
                                                   float* __restrict__ pooled) {
    __shared__ float w_sh[4][64];
    __shared__ int src_sh[4][64];
    __shared__ float red[4][128];
    __shared__ int gsh[4];
    int tid = threadIdx.x, lane = tid & 63, wv = tid >> 6;
    int i = blockIdx.x * 4 + wv;
    int rs = row_ptr[i], deg = row_ptr[i + 1] - rs;
    float ad2i = ad2[i];   // wave-uniform dst projection (expw2 fused)

    f32x2 acc = {0.f, 0.f};
    float den = 0.f;
    if (deg <= 64) {
        if (lane < deg) {
            int s = (int)src_arr[rs + lane];
            float w = __expf(lrelu(as2[s] + ad2i));
            den = w;
            w_sh[wv][lane] = w;
            src_sh[wv][lane] = s;
        }
        __builtin_amdgcn_wave_barrier();
#pragma unroll
        for (int off = 1; off < 64; off <<= 1) den += __shfl_xor(den, off, 64);
        float rden = __builtin_amdgcn_rcpf(den);
        int cnt = deg, eix = 0;
        for (; eix + 7 < cnt; eix += 8) {
            int ss[8];
            float ww[8];
            uint32 uu[8];
#pragma unroll
            for (int q = 0; q < 8; ++q) {
                ss[q] = src_sh[wv][eix + q];
                ww[q] = w_sh[wv][eix + q];
            }
#pragma unroll
            for (int q = 0; q < 8; ++q) uu[q] = h2u[(size_t)ss[q] * 64 + lane];
#pragma unroll
            for (int q = 0; q < 8; ++q) acc = ww[q] * bf2(uu[q]) + acc;
        }
        for (; eix < cnt; ++eix) {
            int s0 = src_sh[wv][eix];
            float w0 = w_sh[wv][eix];
            uint32 u0 = h2u[(size_t)s0 * 64 + lane];
            acc = w0 * bf2(u0) + acc;
        }
        acc *= rden;
    } else {
        for (int eix = lane; eix < deg; eix += 64)
            den += __expf(lrelu(as2[(int)src_arr[rs + eix]] + ad2i));
#pragma unroll
        for (int off = 1; off < 64; off <<= 1) den += __shfl_xor(den, off, 64);
        float rden = __builtin_amdgcn_rcpf(den);
        for (int base = 0; base < deg; base += 64) {
            int cnt = min(deg - base, 64);
            if (lane < cnt) {
                int s = (int)src_arr[rs + base + lane];
                w_sh[wv][lane] = __expf(lrelu(as2[s] + ad2i));
                src_sh[wv][lane] = s;
            }
            __builtin_amdgcn_wave_barrier();
            int eix = 0;
            for (; eix + 7 < cnt; eix += 8) {
                int ss[8];
                float ww[8];
                uint32 uu[8];
#pragma unroll
                for (int q = 0; q < 8; ++q) {
                    ss[q] = src_sh[wv][eix + q];
                    ww[q] = w_sh[wv][eix + q];
                }
#pragma unroll
                for (int q = 0; q < 8; ++q) uu[q] = h2u[(size_t)ss[q] * 64 + lane];
#pragma unroll
                for (int q = 0; q < 8; ++q) acc = ww[q] * bf2(uu[q]) + acc;
            }
            for (; eix < cnt; ++eix) {
                int s0 = src_sh[wv][eix];
                float w0 = w_sh[wv][eix];
                uint32 u0 = h2u[(size_t)s0 * 64 + lane];
                acc = w0 * bf2(u0) + acc;
            }
            __builtin_amdgcn_wave_barrier();
        }
        acc *= rden;
    }
    float2 bv = ((const float2*)b2)[lane];
    float v0 = fmaxf(acc.x + bv.x, 0.f);
    float v1 = fmaxf(acc.y + bv.y, 0.f);
    int g = batch[i];
    // block-level max pre-reduction: batch is sorted, so the block's 4 nodes usually
    // share one graph -> ~4x fewer device-scope atomics.
    red[wv][2 * lane] = v0;
    red[wv][2 * lane + 1] = v1;
    if (lane == 0) gsh[wv] = g;
    __syncthreads();
    bool leader = true;
#pragma unroll
    for (int w2i = 0; w2i < 3; ++w2i)
        if (w2i < wv && gsh[w2i] == g) leader = false;
    if (leader) {
        float m0 = v0, m1 = v1;
#pragma unroll
        for (int w2i = 1; w2i < 4; ++w2i) {
            if (w2i > wv && gsh[w2i] == g) {
                m0 = fmaxf(m0, red[w2i][2 * lane]);
                m1 = fmaxf(m1, red[w2i][2 * lane + 1]);
            }
        }
        atomicMax((int*)&pooled[g * OUT2 + 2 * lane], __float_as_int(m0));
        atomicMax((int*)&pooled[g * OUT2 + 2 * lane + 1], __float_as_int(m1));
    }
}

// ---------------- final FC + relu ----------------
__global__ __launch_bounds__(128) void fc_kernel(const float* __restrict__ pooled,
                                                 const float* __restrict__ fcW,
                                                 const float* __restrict__ fcb,
                                                 float* __restrict__ out) {
    int g = blockIdx.x, tid = threadIdx.x;
    __shared__ float p[128];
    p[tid] = pooled[g * OUT2 + tid];
    __syncthreads();
    float acc = fcb[tid];
    for (int k = 0; k < 128; ++k) acc = fmaf(p[k], fcW[k * OUT2 + tid], acc);
    out[g * OUT2 + tid] = fmaxf(acc, 0.f);
}

extern "C" void kernel_launch(void* const* d_in, const int* in_sizes, int n_in,
                              void* d_out, int out_size, void* d_ws, size_t ws_size,
                              hipStream_t stream) {
    const float* x      = (const float*)d_in[0];
    const int*   ei     = (const int*)d_in[1];
    const int*   batch  = (const int*)d_in[2];
    const float* W1     = (const float*)d_in[4];
    const float* a_src1 = (const float*)d_in[5];
    const float* a_dst1 = (const float*)d_in[6];
    const float* b1     = (const float*)d_in[7];
    const float* W2     = (const float*)d_in[8];
    const float* a_src2 = (const float*)d_in[9];
    const float* a_dst2 = (const float*)d_in[10];
    const float* b2     = (const float*)d_in[11];
    const float* fcW    = (const float*)d_in[12];
    const float* fcb    = (const float*)d_in[13];
    float* out = (float*)d_out;

    size_t off = 0;
    char* base = (char*)d_ws;
    auto alloc = [&](size_t bytes) -> void* {
        void* p = base + off;
        off += (bytes + 255) & ~(size_t)255;
        return p;
    };
    uint32* aggb  = (uint32*)alloc(PL40 * 10 * 4);            // [10][NP][40u]
    u16* h2arena  = (u16*)alloc((size_t)N_NODES * OUT2 * 2);  // h2; xbp aliases early
    u16* h2   = h2arena;
    u16* xbp  = h2arena;                                      // [NP][80 u16] = 8.0 MB < 12.8 MB ✓
    float* asd1 = (float*)alloc((size_t)N_NODES * 20 * 4);
    float* asrc = (float*)alloc((size_t)N_NODES * 12 * 4);    // compact src projections
    float* as2  = (float*)alloc((size_t)N_NODES * 4);
    float* ad2  = (float*)alloc((size_t)N_NODES * 4);
    u16* w1p    = (u16*)alloc((size_t)(10 * 80 * 80) * 2 + 1024);  // + stage slack
    u16* w2p    = (u16*)alloc((size_t)(10 * 128 * 80) * 2);
    u16* VAT    = (u16*)alloc((size_t)32 * 80 * 2);
    float* w2as = (float*)alloc((size_t)D1 * 4);
    float* w2ad = (float*)alloc((size_t)D1 * 4);
    float* pooled = (float*)alloc((size_t)NGRAPH * OUT2 * 4);
    int* deg     = (int*)alloc((size_t)N_NODES * 4);
    int* row_ptr = (int*)alloc((size_t)(N_NODES + 1) * 4);
    int* rank    = (int*)alloc((size_t)ETOT * 4);
    u16* src_arr = (u16*)alloc((size_t)ETOT * 2);
    int* bsum    = (int*)alloc(196 * 4);
    int* boff    = (int*)alloc(196 * 4);

    hipMemsetAsync(deg, 0, (size_t)N_NODES * 4, stream);
    hipMemsetAsync(pooled, 0, (size_t)NGRAPH * OUT2 * 4, stream);

    prephist_kernel<<<HIST_BLKS + PREP_BLKS + PREP2_BLKS, 256, 0, stream>>>(
        x, W1, W2, xbp, w1p, w2p, ei, deg, rank,
        a_src1, a_dst1, a_src2, a_dst2, VAT, w2as, w2ad);
    scan1_kernel<<<196, 256, 0, stream>>>(deg, row_ptr, bsum);
    scan2_kernel<<<1, 256, 0, stream>>>(bsum, boff);
    scan3_kernel<<<196, 256, 0, stream>>>(row_ptr, boff);
    alsc_kernel<<<HIST_BLKS + ALPHA_BLKS, 256, 0, stream>>>(
        (const uint32*)xbp, (const uint32*)VAT, asd1, asrc,
        ei, row_ptr, rank, src_arr);
    agg1m_kernel<<<N_NODES / 4, 128, 0, stream>>>(row_ptr, src_arr, asrc, asd1,
                                                  (const uint32*)xbp, (u16*)aggb);
    gemmf_kernel<<<NP / 128, 256, 0, stream>>>(aggb, (const uint32*)w1p, (const uint32*)w2p,
                                               b1, w2as, w2ad, h2, as2, ad2);
    agg2_kernel<<<N_NODES / 4, 256, 0, stream>>>(row_ptr, src_arr, as2, ad2,
                                                 (const uint32*)h2, b2, batch, pooled);
    fc_kernel<<<NGRAPH, 128, 0, stream>>>(pooled, fcW, fcb, out);
}